// Round 10
// baseline (422.513 us; speedup 1.0000x reference)
//
#include <hip/hip_runtime.h>
#include <hip/hip_bf16.h>
#include <math.h>

typedef unsigned short u16;
typedef unsigned char u8;
typedef __attribute__((ext_vector_type(8))) short bf16x8;
typedef __attribute__((ext_vector_type(4))) float f32x4;
typedef __attribute__((ext_vector_type(2))) float f32x2;
typedef _Float16 f16;
typedef __attribute__((ext_vector_type(2))) _Float16 f16x2;

#if __has_builtin(__builtin_amdgcn_cvt_pk_f32_fp8) && __has_builtin(__builtin_amdgcn_cvt_pk_fp8_f32)
#define HAS_FP8 1
#else
#define HAS_FP8 0
#endif
#if __has_builtin(__builtin_amdgcn_fdot2)
#define HAS_FDOT2 1
#else
#define HAS_FDOT2 0
#endif

__device__ __forceinline__ u16 f2bf(float f) {
    unsigned u = __float_as_uint(f);
    u += 0x7fffu + ((u >> 16) & 1u);   // RNE
    return (u16)(u >> 16);
}
__device__ __forceinline__ float bf2f(u16 h) {
    return __uint_as_float(((unsigned)h) << 16);
}
__device__ __forceinline__ u16 f2h(float f) {
    return __builtin_bit_cast(u16, (f16)f);   // v_cvt_f16_f32 (RNE)
}
__device__ __forceinline__ f16x2 u2h(int u) {
    return __builtin_bit_cast(f16x2, u);
}

// ---------------------------------------------------------------------------
// prep_misc: grid-partitioned fusion of {convert W1, convert W2, zero deg}.
// wt[832][64] bf16 (cols 0-255 q *0.125 folded, 256-511 k, 512-767 v,
// 768-831 s), bias ba[832] fp32 (q part *0.125).
// ---------------------------------------------------------------------------
__device__ __forceinline__ void conv_w_one(
    int idx,
    const float* __restrict__ Wq, const float* __restrict__ Wk,
    const float* __restrict__ Wv, const float* __restrict__ Ws,
    const float* __restrict__ bq, const float* __restrict__ bk,
    const float* __restrict__ bv, const float* __restrict__ bs,
    u16* __restrict__ wt, float* __restrict__ ba)
{
    int col = idx >> 6, k = idx & 63;
    float w;
    if      (col < 256) w = Wq[k * 256 + col] * 0.125f;          // fold 1/sqrt(C)
    else if (col < 512) w = Wk[k * 256 + (col - 256)];
    else if (col < 768) w = Wv[k * 256 + (col - 512)];
    else                w = Ws[k * 64  + (col - 768)];
    wt[col * 64 + k] = f2bf(w);
    if (k == 0)
        ba[col] = (col < 256) ? bq[col] * 0.125f : (col < 512) ? bk[col - 256]
                 : (col < 768) ? bv[col - 512] : bs[col - 768];
}

__global__ __launch_bounds__(256) void prep_misc(
    const float* __restrict__ Wq1, const float* __restrict__ Wk1,
    const float* __restrict__ Wv1, const float* __restrict__ Ws1,
    const float* __restrict__ bq1, const float* __restrict__ bk1,
    const float* __restrict__ bv1, const float* __restrict__ bs1,
    const float* __restrict__ Wq2, const float* __restrict__ Wk2,
    const float* __restrict__ Wv2, const float* __restrict__ Ws2,
    const float* __restrict__ bq2, const float* __restrict__ bk2,
    const float* __restrict__ bv2, const float* __restrict__ bs2,
    u16* __restrict__ wt1, float* __restrict__ ba1,
    u16* __restrict__ wt2, float* __restrict__ ba2,
    int* __restrict__ deg, int n)
{
    int b = blockIdx.x, t = threadIdx.x;
    if (b < 208) {
        conv_w_one(b * 256 + t, Wq1, Wk1, Wv1, Ws1, bq1, bk1, bv1, bs1, wt1, ba1);
    } else if (b < 416) {
        conv_w_one((b - 208) * 256 + t, Wq2, Wk2, Wv2, Ws2, bq2, bk2, bv2, bs2, wt2, ba2);
    } else {
        int i = (b - 416) * 256 + t;
        if (i < n) deg[i] = 0;
    }
}

// ---------------------------------------------------------------------------
// CSR build: histogram, 3-phase coalesced scan, fill
// ---------------------------------------------------------------------------
__global__ __launch_bounds__(256) void hist_kernel(
    const int* __restrict__ dst, int* __restrict__ deg, int E)
{
    int e = blockIdx.x * 256 + threadIdx.x;
    if (e < E) atomicAdd(&deg[dst[e]], 1);
}

__global__ __launch_bounds__(256) void scanA(
    const int* __restrict__ deg, int* __restrict__ bsum, int n)
{
    int i = blockIdx.x * 256 + threadIdx.x;
    int v = (i < n) ? deg[i] : 0;
    #pragma unroll
    for (int o = 32; o; o >>= 1) v += __shfl_xor(v, o);
    __shared__ int wsum[4];
    if ((threadIdx.x & 63) == 0) wsum[threadIdx.x >> 6] = v;
    __syncthreads();
    if (threadIdx.x == 0)
        bsum[blockIdx.x] = wsum[0] + wsum[1] + wsum[2] + wsum[3];
}

__global__ __launch_bounds__(256) void scanB(
    const int* __restrict__ bsum, int* __restrict__ bpre, int nb)
{
    int t = threadIdx.x;
    int v = (t < nb) ? bsum[t] : 0;
    int lane = t & 63, wv = t >> 6;
    int sv = v;
    #pragma unroll
    for (int o = 1; o < 64; o <<= 1) {
        int u = __shfl_up(sv, o);
        if (lane >= o) sv += u;
    }
    __shared__ int wsum[4];
    if (lane == 63) wsum[wv] = sv;
    __syncthreads();
    int add = 0;
    for (int k = 0; k < wv; ++k) add += wsum[k];
    if (t < nb) bpre[t] = sv + add - v;   // exclusive
}

__global__ __launch_bounds__(256) void scanC(
    const int* __restrict__ deg, const int* __restrict__ bpre,
    int* __restrict__ off, int* __restrict__ cursor, int n, int E)
{
    int i = blockIdx.x * 256 + threadIdx.x;
    int v = (i < n) ? deg[i] : 0;
    int lane = threadIdx.x & 63, wv = threadIdx.x >> 6;
    int sv = v;
    #pragma unroll
    for (int o = 1; o < 64; o <<= 1) {
        int u = __shfl_up(sv, o);
        if (lane >= o) sv += u;
    }
    __shared__ int wsum[4];
    if (lane == 63) wsum[wv] = sv;
    __syncthreads();
    int add = bpre[blockIdx.x];
    for (int k = 0; k < wv; ++k) add += wsum[k];
    int excl = add + sv - v;
    if (i < n) {
        off[i] = excl; cursor[i] = excl;
        if (i == n - 1) off[n] = E;
    }
}

__global__ __launch_bounds__(256) void fill_kernel(
    const int* __restrict__ src, const int* __restrict__ dst,
    int* __restrict__ cursor, int* __restrict__ csr_src, int E)
{
    int e = blockIdx.x * 256 + threadIdx.x;
    if (e >= E) return;
    int slot = atomicAdd(&cursor[dst[e]], 1);
    csr_src[slot] = src[e];
}

// ---------------------------------------------------------------------------
// bf16 MFMA GEMM, W as A-operand / X as B-operand; each lane owns 4
// consecutive output cols of one node. q/v stored f16, k stored fp8-e4m3
// (halves the attn k-gather), skip stored f16. FP32IN: fp32 X in-register cvt.
// ---------------------------------------------------------------------------
template <int FP32IN>
__global__ __launch_bounds__(256) void gemm_qkvs(
    const void* __restrict__ Xv, const u16* __restrict__ wt,
    const float* __restrict__ ba,
    u16* __restrict__ qb, u8* __restrict__ kb8, u16* __restrict__ vb,
    u16* __restrict__ skip, int n)
{
    const int w = threadIdx.x >> 6, lane = threadIdx.x & 63;
    const int r = lane & 15, g = lane >> 4;
    const int node0 = blockIdx.x * 16;

    int nr = node0 + r; if (nr >= n) nr = n - 1;
    bf16x8 b0, b1;                            // X fragment (B operand)
    if (FP32IN) {
        const float* xr = (const float*)Xv + (size_t)nr * 64 + g * 8;
        float t0[8], t1[8];
        *(float4*)(t0)     = ((const float4*)xr)[0];
        *(float4*)(t0 + 4) = ((const float4*)xr)[1];
        *(float4*)(t1)     = ((const float4*)(xr + 32))[0];
        *(float4*)(t1 + 4) = ((const float4*)(xr + 32))[1];
        #pragma unroll
        for (int j = 0; j < 8; ++j) {
            b0[j] = (short)f2bf(t0[j]);
            b1[j] = (short)f2bf(t1[j]);
        }
    } else {
        const u16* xr = (const u16*)Xv + (size_t)nr * 64 + g * 8;
        b0 = *(const bf16x8*)xr;
        b1 = *(const bf16x8*)(xr + 32);
    }

    const int colbase = w * 208;
    const int node = node0 + r;

    const u16* wr0 = wt + (size_t)(colbase + r) * 64 + g * 8;
    bf16x8 a0 = *(const bf16x8*)wr0;
    bf16x8 a1 = *(const bf16x8*)(wr0 + 32);

    for (int ct = 0; ct < 13; ++ct) {
        int ctn = (ct + 1 < 13) ? ct + 1 : 12;
        const u16* wrn = wt + (size_t)(colbase + ctn * 16 + r) * 64 + g * 8;
        bf16x8 an0 = *(const bf16x8*)wrn;
        bf16x8 an1 = *(const bf16x8*)(wrn + 32);

        f32x4 acc = {0.f, 0.f, 0.f, 0.f};
        acc = __builtin_amdgcn_mfma_f32_16x16x32_bf16(a0, b0, acc, 0, 0, 0);
        acc = __builtin_amdgcn_mfma_f32_16x16x32_bf16(a1, b1, acc, 0, 0, 0);
        int col0 = colbase + ct * 16 + g * 4;
        float4 bias = *(const float4*)(ba + col0);
        if (node < n) {
            float v0 = acc[0] + bias.x, v1 = acc[1] + bias.y;
            float v2 = acc[2] + bias.z, v3 = acc[3] + bias.w;
            if (col0 < 256) {
                ushort4 o;
                o.x = f2h(v0); o.y = f2h(v1); o.z = f2h(v2); o.w = f2h(v3);
                *(ushort4*)(qb + (size_t)node * 256 + col0) = o;
            } else if (col0 < 512) {
                int c = col0 - 256;
#if HAS_FP8
                unsigned pk = __builtin_amdgcn_cvt_pk_fp8_f32(v0, v1, 0u, false);
                pk = __builtin_amdgcn_cvt_pk_fp8_f32(v2, v3, pk, true);
                *(unsigned*)(kb8 + (size_t)node * 256 + c) = pk;
#else
                ushort4 o;
                o.x = f2h(v0); o.y = f2h(v1); o.z = f2h(v2); o.w = f2h(v3);
                *(ushort4*)((u16*)kb8 + (size_t)node * 256 + c) = o;
#endif
            } else if (col0 < 768) {
                int c = col0 - 512;
                ushort4 o;
                o.x = f2h(v0); o.y = f2h(v1); o.z = f2h(v2); o.w = f2h(v3);
                *(ushort4*)(vb + (size_t)node * 256 + c) = o;
            } else {
                ushort4 o;
                o.x = f2h(v0); o.y = f2h(v1); o.z = f2h(v2); o.w = f2h(v3);
                *(ushort4*)(skip + (size_t)node * 64 + (col0 - 768)) = o;
            }
        }
        a0 = an0; a1 = an1;
    }
}

// ---------------------------------------------------------------------------
// Fused attention: ONE node per wave, TWO edge-streams (half-wave each,
// edges t = 2i+half). k rows fp8-e4m3 (8B/lane), v rows f16 (16B/lane),
// defer-max rescale (THR=8), clamped 3-deep prefetch.
// ---------------------------------------------------------------------------
template <int RELU, int BF16OUT>
__global__ __launch_bounds__(256) void fused_attn(
    const u16* __restrict__ qb, const u8* __restrict__ kb8,
    const u16* __restrict__ vb, const u16* __restrict__ skip,
    const int* __restrict__ off, const int* __restrict__ csr,
    const float* __restrict__ lng, const float* __restrict__ lnb,
    u16* __restrict__ out_bf, float* __restrict__ out_f, int n)
{
    const int lane = threadIdx.x & 63;
    const int half = lane >> 5;          // edge-stream parity
    const int hl   = lane & 31;          // h*8 + c8
    const int c8   = lane & 7;
    const int node = blockIdx.x * 4 + (threadIdx.x >> 6);
    const bool nvalid = node < n;
    const int nodeC = nvalid ? node : n - 1;

    // q: decode f16 row slice to f32 (1/sqrt(C) pre-folded into Wq)
    const int4 qw = *(const int4*)(qb + (size_t)nodeC * 256 + hl * 8);
    float qf[8];
    {
        f16x2 t0 = u2h(qw.x), t1 = u2h(qw.y), t2 = u2h(qw.z), t3 = u2h(qw.w);
        qf[0] = (float)t0.x; qf[1] = (float)t0.y;
        qf[2] = (float)t1.x; qf[3] = (float)t1.y;
        qf[4] = (float)t2.x; qf[5] = (float)t2.y;
        qf[6] = (float)t3.x; qf[7] = (float)t3.y;
    }

    const int s0 = off[nodeC], s1 = off[nodeC + 1];
    const int deg = nvalid ? (s1 - s0) : 0;
    const int imax = (deg + 1) >> 1;     // iterations per stream

    float m = -1e30f, l = 0.f;
    float a[8] = {0.f, 0.f, 0.f, 0.f, 0.f, 0.f, 0.f, 0.f};

    if (imax > 0) {
#if HAS_FP8
        const u8* kbase = kb8 + hl * 8;
        typedef uint2 kreg_t;
#else
        const u16* kbase = (const u16*)kb8 + hl * 8;
        typedef int4 kreg_t;
#endif
        const u16* vbase = vb + hl * 8;
        // clamped: tail loads re-read row csr[s1-1] (cache-hot, masked out)
        #define LOADKV(I, K, V) { \
            int _ix = min(s0 + 2 * (I) + half, s1 - 1); \
            int _s = csr[_ix]; \
            K = *(const kreg_t*)(kbase + (size_t)_s * 256); \
            V = *(const int4*)(vbase + (size_t)_s * 256); }

        kreg_t k0, k1, k2;
        int4 v0, v1, v2;
        LOADKV(0, k0, v0);
        LOADKV(1, k1, v1);
        LOADKV(2, k2, v2);

        #pragma unroll 3
        for (int i = 0; i < imax; ++i) {
            kreg_t kn; int4 vn;
            LOADKV(i + 3, kn, vn);

            float p = 0.f;
#if HAS_FP8
            {
                f32x2 d0 = __builtin_amdgcn_cvt_pk_f32_fp8(k0.x, false);
                f32x2 d1 = __builtin_amdgcn_cvt_pk_f32_fp8(k0.x, true);
                f32x2 d2 = __builtin_amdgcn_cvt_pk_f32_fp8(k0.y, false);
                f32x2 d3 = __builtin_amdgcn_cvt_pk_f32_fp8(k0.y, true);
                p = fmaf(d0.x, qf[0], p); p = fmaf(d0.y, qf[1], p);
                p = fmaf(d1.x, qf[2], p); p = fmaf(d1.y, qf[3], p);
                p = fmaf(d2.x, qf[4], p); p = fmaf(d2.y, qf[5], p);
                p = fmaf(d3.x, qf[6], p); p = fmaf(d3.y, qf[7], p);
            }
#else
            {
                f16x2 t0 = u2h(k0.x), t1 = u2h(k0.y), t2 = u2h(k0.z), t3 = u2h(k0.w);
                p = fmaf((float)t0.x, qf[0], p); p = fmaf((float)t0.y, qf[1], p);
                p = fmaf((float)t1.x, qf[2], p); p = fmaf((float)t1.y, qf[3], p);
                p = fmaf((float)t2.x, qf[4], p); p = fmaf((float)t2.y, qf[5], p);
                p = fmaf((float)t3.x, qf[6], p); p = fmaf((float)t3.y, qf[7], p);
            }
#endif
            p += __shfl_xor(p, 1);
            p += __shfl_xor(p, 2);
            p += __shfl_xor(p, 4);
            p = (2 * i + half < deg) ? p : -2e30f;   // tail mask

            f16x2 va0 = u2h(v0.x), va1 = u2h(v0.y);
            f16x2 va2 = u2h(v0.z), va3 = u2h(v0.w);
            if (__all(p - m <= 8.f)) {
                // defer-max fast path: no rescale (P bounded by e^8)
                float e = __expf(p - m);
                l += e;
                a[0] = fmaf(e, (float)va0.x, a[0]);
                a[1] = fmaf(e, (float)va0.y, a[1]);
                a[2] = fmaf(e, (float)va1.x, a[2]);
                a[3] = fmaf(e, (float)va1.y, a[3]);
                a[4] = fmaf(e, (float)va2.x, a[4]);
                a[5] = fmaf(e, (float)va2.y, a[5]);
                a[6] = fmaf(e, (float)va3.x, a[6]);
                a[7] = fmaf(e, (float)va3.y, a[7]);
            } else {
                float nm = fmaxf(m, p);
                float c = __expf(m - nm);
                float e = __expf(p - nm);
                m = nm;
                l = l * c + e;
                a[0] = fmaf(e, (float)va0.x, a[0] * c);
                a[1] = fmaf(e, (float)va0.y, a[1] * c);
                a[2] = fmaf(e, (float)va1.x, a[2] * c);
                a[3] = fmaf(e, (float)va1.y, a[3] * c);
                a[4] = fmaf(e, (float)va2.x, a[4] * c);
                a[5] = fmaf(e, (float)va2.y, a[5] * c);
                a[6] = fmaf(e, (float)va3.x, a[6] * c);
                a[7] = fmaf(e, (float)va3.y, a[7] * c);
            }

            k0 = k1; v0 = v1; k1 = k2; v1 = v2; k2 = kn; v2 = vn;
        }
        #undef LOADKV
    }

    // merge the two streams (lane ^ 32 holds the partner state)
    {
        float mo = __shfl_xor(m, 32);
        float lo_ = __shfl_xor(l, 32);
        float nm = fmaxf(m, mo);
        float c  = __expf(m - nm);
        float co = __expf(mo - nm);
        l = l * c + lo_ * co;
        #pragma unroll
        for (int j = 0; j < 8; ++j) {
            float ao = __shfl_xor(a[j], 32);
            a[j] = a[j] * c + ao * co;
        }
    }

    // normalize per head, then mean over heads (hl bits 3,4)
    const float inv = 0.25f / (l + 1e-16f);
    #pragma unroll
    for (int j = 0; j < 8; ++j) {
        a[j] *= inv;
        a[j] += __shfl_xor(a[j], 8);
        a[j] += __shfl_xor(a[j], 16);
    }

    // skip connection (f16): channels c8*8 .. +7
    const int4 skw = *(const int4*)(skip + (size_t)nodeC * 64 + c8 * 8);
    f16x2 s0_ = u2h(skw.x), s1_ = u2h(skw.y), s2_ = u2h(skw.z), s3_ = u2h(skw.w);
    float o[8];
    o[0] = a[0] + (float)s0_.x; o[1] = a[1] + (float)s0_.y;
    o[2] = a[2] + (float)s1_.x; o[3] = a[3] + (float)s1_.y;
    o[4] = a[4] + (float)s2_.x; o[5] = a[5] + (float)s2_.y;
    o[6] = a[6] + (float)s3_.x; o[7] = a[7] + (float)s3_.y;

    // LayerNorm over 64 channels (8 lanes x 8 ch within each 8-lane group)
    float s = o[0] + o[1] + o[2] + o[3] + o[4] + o[5] + o[6] + o[7];
    s += __shfl_xor(s, 1); s += __shfl_xor(s, 2); s += __shfl_xor(s, 4);
    const float mu = s * (1.f / 64.f);
    float vs = 0.f;
    #pragma unroll
    for (int j = 0; j < 8; ++j) { o[j] -= mu; vs = fmaf(o[j], o[j], vs); }
    vs += __shfl_xor(vs, 1); vs += __shfl_xor(vs, 2); vs += __shfl_xor(vs, 4);
    const float rs = rsqrtf(vs * (1.f / 64.f) + 1e-5f);

    const float4* gp = (const float4*)(lng + c8 * 8);
    const float4* bp = (const float4*)(lnb + c8 * 8);
    float4 g0 = gp[0], g1 = gp[1], b0 = bp[0], b1 = bp[1];
    float y[8];
    y[0] = o[0] * rs * g0.x + b0.x; y[1] = o[1] * rs * g0.y + b0.y;
    y[2] = o[2] * rs * g0.z + b0.z; y[3] = o[3] * rs * g0.w + b0.w;
    y[4] = o[4] * rs * g1.x + b1.x; y[5] = o[5] * rs * g1.y + b1.y;
    y[6] = o[6] * rs * g1.z + b1.z; y[7] = o[7] * rs * g1.w + b1.w;
    if (RELU) {
        #pragma unroll
        for (int j = 0; j < 8; ++j) y[j] = fmaxf(y[j], 0.f);
    }

    if (lane < 8 && nvalid) {
        if (BF16OUT) {
            bf16x8 ob;
            #pragma unroll
            for (int j = 0; j < 8; ++j) ob[j] = (short)f2bf(y[j]);
            *(bf16x8*)(out_bf + (size_t)node * 64 + c8 * 8) = ob;
        } else {
            float4* op = (float4*)(out_f + (size_t)node * 64 + c8 * 8);
            op[0] = make_float4(y[0], y[1], y[2], y[3]);
            op[1] = make_float4(y[4], y[5], y[6], y[7]);
        }
    }
}

// ---------------------------------------------------------------------------
// Final Linear 64->32 (LN already applied by fused_attn<0,0>)
// ---------------------------------------------------------------------------
__global__ __launch_bounds__(256) void final_matvec(
    const float* __restrict__ y, const float* __restrict__ Wf,
    const float* __restrict__ bfv, float* __restrict__ out, int n)
{
    __shared__ float ys[8][64];
    int nb = blockIdx.x * 8;
    for (int i = threadIdx.x; i < 512; i += 256) {
        int r = i >> 6, c = i & 63;
        int gn = nb + r;
        ys[r][c] = (gn < n) ? y[(size_t)gn * 64 + c] : 0.f;
    }
    __syncthreads();
    int r = threadIdx.x >> 5, o = threadIdx.x & 31;
    int gn = nb + r;
    if (gn < n) {
        float a = bfv[o];
        #pragma unroll
        for (int c = 0; c < 64; ++c) a = fmaf(ys[r][c], Wf[c * 32 + o], a);
        out[(size_t)gn * 32 + o] = a;
    }
}

// ---------------------------------------------------------------------------
extern "C" void kernel_launch(void* const* d_in, const int* in_sizes, int n_in,
                              void* d_out, int out_size, void* d_ws, size_t ws_size,
                              hipStream_t stream)
{
    const float* x   = (const float*)d_in[0];
    const int*   ei  = (const int*)d_in[1];
    const float* Wq1 = (const float*)d_in[2];  const float* bq1 = (const float*)d_in[3];
    const float* Wk1 = (const float*)d_in[4];  const float* bk1 = (const float*)d_in[5];
    const float* Wv1 = (const float*)d_in[6];  const float* bv1 = (const float*)d_in[7];
    const float* Ws1 = (const float*)d_in[8];  const float* bs1 = (const float*)d_in[9];
    const float* Wq2 = (const float*)d_in[10]; const float* bq2 = (const float*)d_in[11];
    const float* Wk2 = (const float*)d_in[12]; const float* bk2 = (const float*)d_in[13];
    const float* Wv2 = (const float*)d_in[14]; const float* bv2 = (const float*)d_in[15];
    const float* Ws2 = (const float*)d_in[16]; const float* bs2 = (const float*)d_in[17];
    const float* lng = (const float*)d_in[18]; const float* lnb = (const float*)d_in[19];
    const float* Wf  = (const float*)d_in[20]; const float* bf  = (const float*)d_in[21];

    const int N = in_sizes[0] / 64;
    const int E = in_sizes[1] / 2;
    const int* src  = ei;
    const int* dstp = ei + E;

    char* p = (char*)d_ws;
    u16* qb   = (u16*)p; p += (size_t)N * 256 * 2;   // f16
    u8*  kb8  = (u8*)p;  p += (size_t)N * 256 * 2;   // fp8 (f16 fallback fits too)
    u16* vb   = (u16*)p; p += (size_t)N * 256 * 2;   // f16
    u16* xbf  = (u16*)p; p += (size_t)N * 64 * 2;    // conv1 output h (bf16)
    u16* wt1  = (u16*)p; p += 832 * 64 * 2;
    u16* wt2  = (u16*)p; p += 832 * 64 * 2;
    float* ba1  = (float*)p; p += 832 * 4;
    float* ba2  = (float*)p; p += 832 * 4;
    u16* skip = (u16*)p; p += (size_t)N * 64 * 2;    // f16
    float* y2   = (float*)p; p += (size_t)N * 64 * 4;
    int* deg    = (int*)p; p += (size_t)N * 4;
    int* off    = (int*)p; p += ((size_t)N + 1) * 4;
    int* cursor = (int*)p; p += (size_t)N * 4;
    int* csr    = (int*)p; p += (size_t)E * 4;
    int* bsum   = (int*)p; p += 1024;
    int* bpre   = (int*)p; p += 1024;

    const int e_blocks    = (E + 255) / 256;
    const int n_blocks    = (N + 255) / 256;
    const int prep_blocks = 416 + n_blocks;
    const int gemm_blocks = (N + 15) / 16;
    const int attn_blocks = (N + 3) / 4;            // 1 node/wave, 4 waves/blk
    const int fin_blocks  = (N + 7) / 8;

    // ---- prep: fused conversions + CSR ----
    prep_misc<<<prep_blocks, 256, 0, stream>>>(
        Wq1, Wk1, Wv1, Ws1, bq1, bk1, bv1, bs1,
        Wq2, Wk2, Wv2, Ws2, bq2, bk2, bv2, bs2,
        wt1, ba1, wt2, ba2, deg, N);
    hist_kernel<<<e_blocks, 256, 0, stream>>>(dstp, deg, E);
    scanA<<<n_blocks, 256, 0, stream>>>(deg, bsum, N);
    scanB<<<1, 256, 0, stream>>>(bsum, bpre, n_blocks);
    scanC<<<n_blocks, 256, 0, stream>>>(deg, bpre, off, cursor, N, E);
    fill_kernel<<<e_blocks, 256, 0, stream>>>(src, dstp, cursor, csr, E);

    // ---- conv1 (reads fp32 x directly) ----
    gemm_qkvs<1><<<gemm_blocks, 256, 0, stream>>>(x, wt1, ba1, qb, kb8, vb, skip, N);
    fused_attn<1, 1><<<attn_blocks, 256, 0, stream>>>(qb, kb8, vb, skip, off, csr,
                                                      lng, lnb, xbf, nullptr, N);
    // ---- conv2 ----
    gemm_qkvs<0><<<gemm_blocks, 256, 0, stream>>>(xbf, wt2, ba2, qb, kb8, vb, skip, N);
    fused_attn<0, 0><<<attn_blocks, 256, 0, stream>>>(qb, kb8, vb, skip, off, csr,
                                                      lng, lnb, nullptr, y2, N);
    // ---- final linear ----
    final_matvec<<<fin_blocks, 256, 0, stream>>>(y2, Wf, bf, (float*)d_out, N);
}

// Round 11
// 421.814 us; speedup vs baseline: 1.0017x; 1.0017x over previous
//
#include <hip/hip_runtime.h>
#include <hip/hip_bf16.h>
#include <math.h>

typedef unsigned short u16;
typedef unsigned char u8;
typedef __attribute__((ext_vector_type(8))) short bf16x8;
typedef __attribute__((ext_vector_type(4))) float f32x4;
typedef __attribute__((ext_vector_type(2))) float f32x2;
typedef _Float16 f16;
typedef __attribute__((ext_vector_type(2))) _Float16 f16x2;

#if __has_builtin(__builtin_amdgcn_cvt_pk_f32_fp8) && __has_builtin(__builtin_amdgcn_cvt_pk_fp8_f32)
#define HAS_FP8 1
#else
#define HAS_FP8 0
#endif

__device__ __forceinline__ u16 f2bf(float f) {
    unsigned u = __float_as_uint(f);
    u += 0x7fffu + ((u >> 16) & 1u);   // RNE
    return (u16)(u >> 16);
}
__device__ __forceinline__ u16 f2h(float f) {
    return __builtin_bit_cast(u16, (f16)f);   // v_cvt_f16_f32 (RNE)
}
__device__ __forceinline__ f16x2 u2h(int u) {
    return __builtin_bit_cast(f16x2, u);
}

#if HAS_FP8
typedef uint2 kreg_t;
__device__ __forceinline__ float dotqk(kreg_t K, const float qf[8]) {
    f32x2 d0 = __builtin_amdgcn_cvt_pk_f32_fp8(K.x, false);
    f32x2 d1 = __builtin_amdgcn_cvt_pk_f32_fp8(K.x, true);
    f32x2 d2 = __builtin_amdgcn_cvt_pk_f32_fp8(K.y, false);
    f32x2 d3 = __builtin_amdgcn_cvt_pk_f32_fp8(K.y, true);
    float p = d0.x * qf[0];
    p = fmaf(d0.y, qf[1], p); p = fmaf(d1.x, qf[2], p); p = fmaf(d1.y, qf[3], p);
    p = fmaf(d2.x, qf[4], p); p = fmaf(d2.y, qf[5], p);
    p = fmaf(d3.x, qf[6], p); p = fmaf(d3.y, qf[7], p);
    return p;
}
#else
typedef int4 kreg_t;
__device__ __forceinline__ float dotqk(kreg_t K, const float qf[8]) {
    f16x2 t0 = u2h(K.x), t1 = u2h(K.y), t2 = u2h(K.z), t3 = u2h(K.w);
    float p = (float)t0.x * qf[0];
    p = fmaf((float)t0.y, qf[1], p); p = fmaf((float)t1.x, qf[2], p);
    p = fmaf((float)t1.y, qf[3], p); p = fmaf((float)t2.x, qf[4], p);
    p = fmaf((float)t2.y, qf[5], p); p = fmaf((float)t3.x, qf[6], p);
    p = fmaf((float)t3.y, qf[7], p);
    return p;
}
#endif

// ---------------------------------------------------------------------------
// prep_misc: grid-partitioned fusion of {convert W1, convert W2, zero deg}.
// wt[832][64] bf16 (cols 0-255 q *0.125 folded, 256-511 k, 512-767 v,
// 768-831 s), bias ba[832] fp32 (q part *0.125).
// ---------------------------------------------------------------------------
__device__ __forceinline__ void conv_w_one(
    int idx,
    const float* __restrict__ Wq, const float* __restrict__ Wk,
    const float* __restrict__ Wv, const float* __restrict__ Ws,
    const float* __restrict__ bq, const float* __restrict__ bk,
    const float* __restrict__ bv, const float* __restrict__ bs,
    u16* __restrict__ wt, float* __restrict__ ba)
{
    int col = idx >> 6, k = idx & 63;
    float w;
    if      (col < 256) w = Wq[k * 256 + col] * 0.125f;          // fold 1/sqrt(C)
    else if (col < 512) w = Wk[k * 256 + (col - 256)];
    else if (col < 768) w = Wv[k * 256 + (col - 512)];
    else                w = Ws[k * 64  + (col - 768)];
    wt[col * 64 + k] = f2bf(w);
    if (k == 0)
        ba[col] = (col < 256) ? bq[col] * 0.125f : (col < 512) ? bk[col - 256]
                 : (col < 768) ? bv[col - 512] : bs[col - 768];
}

__global__ __launch_bounds__(256) void prep_misc(
    const float* __restrict__ Wq1, const float* __restrict__ Wk1,
    const float* __restrict__ Wv1, const float* __restrict__ Ws1,
    const float* __restrict__ bq1, const float* __restrict__ bk1,
    const float* __restrict__ bv1, const float* __restrict__ bs1,
    const float* __restrict__ Wq2, const float* __restrict__ Wk2,
    const float* __restrict__ Wv2, const float* __restrict__ Ws2,
    const float* __restrict__ bq2, const float* __restrict__ bk2,
    const float* __restrict__ bv2, const float* __restrict__ bs2,
    u16* __restrict__ wt1, float* __restrict__ ba1,
    u16* __restrict__ wt2, float* __restrict__ ba2,
    int* __restrict__ deg, int n)
{
    int b = blockIdx.x, t = threadIdx.x;
    if (b < 208) {
        conv_w_one(b * 256 + t, Wq1, Wk1, Wv1, Ws1, bq1, bk1, bv1, bs1, wt1, ba1);
    } else if (b < 416) {
        conv_w_one((b - 208) * 256 + t, Wq2, Wk2, Wv2, Ws2, bq2, bk2, bv2, bs2, wt2, ba2);
    } else {
        int i = (b - 416) * 256 + t;
        if (i < n) deg[i] = 0;
    }
}

// ---------------------------------------------------------------------------
// CSR scan (3-phase coalesced) + fill
// ---------------------------------------------------------------------------
__global__ __launch_bounds__(256) void scanA(
    const int* __restrict__ deg, int* __restrict__ bsum, int n)
{
    int i = blockIdx.x * 256 + threadIdx.x;
    int v = (i < n) ? deg[i] : 0;
    #pragma unroll
    for (int o = 32; o; o >>= 1) v += __shfl_xor(v, o);
    __shared__ int wsum[4];
    if ((threadIdx.x & 63) == 0) wsum[threadIdx.x >> 6] = v;
    __syncthreads();
    if (threadIdx.x == 0)
        bsum[blockIdx.x] = wsum[0] + wsum[1] + wsum[2] + wsum[3];
}

__global__ __launch_bounds__(256) void scanB(
    const int* __restrict__ bsum, int* __restrict__ bpre, int nb)
{
    int t = threadIdx.x;
    int v = (t < nb) ? bsum[t] : 0;
    int lane = t & 63, wv = t >> 6;
    int sv = v;
    #pragma unroll
    for (int o = 1; o < 64; o <<= 1) {
        int u = __shfl_up(sv, o);
        if (lane >= o) sv += u;
    }
    __shared__ int wsum[4];
    if (lane == 63) wsum[wv] = sv;
    __syncthreads();
    int add = 0;
    for (int k = 0; k < wv; ++k) add += wsum[k];
    if (t < nb) bpre[t] = sv + add - v;   // exclusive
}

__global__ __launch_bounds__(256) void scanC(
    const int* __restrict__ deg, const int* __restrict__ bpre,
    int* __restrict__ off, int* __restrict__ cursor, int n, int E)
{
    int i = blockIdx.x * 256 + threadIdx.x;
    int v = (i < n) ? deg[i] : 0;
    int lane = threadIdx.x & 63, wv = threadIdx.x >> 6;
    int sv = v;
    #pragma unroll
    for (int o = 1; o < 64; o <<= 1) {
        int u = __shfl_up(sv, o);
        if (lane >= o) sv += u;
    }
    __shared__ int wsum[4];
    if (lane == 63) wsum[wv] = sv;
    __syncthreads();
    int add = bpre[blockIdx.x];
    for (int k = 0; k < wv; ++k) add += wsum[k];
    int excl = add + sv - v;
    if (i < n) {
        off[i] = excl; cursor[i] = excl;
        if (i == n - 1) off[n] = E;
    }
}

__global__ __launch_bounds__(256) void fill_kernel(
    const int* __restrict__ src, const int* __restrict__ dst,
    int* __restrict__ cursor, int* __restrict__ csr_src, int E)
{
    int e = blockIdx.x * 256 + threadIdx.x;
    if (e >= E) return;
    int slot = atomicAdd(&cursor[dst[e]], 1);
    csr_src[slot] = src[e];
}

// ---------------------------------------------------------------------------
// bf16 MFMA GEMM body (device fn). W as A-operand / X as B-operand; each
// lane owns 4 consecutive output cols of one node. q/v f16, k fp8, skip f16.
// ---------------------------------------------------------------------------
template <int FP32IN>
__device__ __forceinline__ void gemm_body(
    int blk, const void* __restrict__ Xv, const u16* __restrict__ wt,
    const float* __restrict__ ba,
    u16* __restrict__ qb, u8* __restrict__ kb8, u16* __restrict__ vb,
    u16* __restrict__ skip, int n)
{
    const int w = threadIdx.x >> 6, lane = threadIdx.x & 63;
    const int r = lane & 15, g = lane >> 4;
    const int node0 = blk * 16;

    int nr = node0 + r; if (nr >= n) nr = n - 1;
    bf16x8 b0, b1;                            // X fragment (B operand)
    if (FP32IN) {
        const float* xr = (const float*)Xv + (size_t)nr * 64 + g * 8;
        float t0[8], t1[8];
        *(float4*)(t0)     = ((const float4*)xr)[0];
        *(float4*)(t0 + 4) = ((const float4*)xr)[1];
        *(float4*)(t1)     = ((const float4*)(xr + 32))[0];
        *(float4*)(t1 + 4) = ((const float4*)(xr + 32))[1];
        #pragma unroll
        for (int j = 0; j < 8; ++j) {
            b0[j] = (short)f2bf(t0[j]);
            b1[j] = (short)f2bf(t1[j]);
        }
    } else {
        const u16* xr = (const u16*)Xv + (size_t)nr * 64 + g * 8;
        b0 = *(const bf16x8*)xr;
        b1 = *(const bf16x8*)(xr + 32);
    }

    const int colbase = w * 208;
    const int node = node0 + r;

    const u16* wr0 = wt + (size_t)(colbase + r) * 64 + g * 8;
    bf16x8 a0 = *(const bf16x8*)wr0;
    bf16x8 a1 = *(const bf16x8*)(wr0 + 32);

    for (int ct = 0; ct < 13; ++ct) {
        int ctn = (ct + 1 < 13) ? ct + 1 : 12;
        const u16* wrn = wt + (size_t)(colbase + ctn * 16 + r) * 64 + g * 8;
        bf16x8 an0 = *(const bf16x8*)wrn;
        bf16x8 an1 = *(const bf16x8*)(wrn + 32);

        f32x4 acc = {0.f, 0.f, 0.f, 0.f};
        acc = __builtin_amdgcn_mfma_f32_16x16x32_bf16(a0, b0, acc, 0, 0, 0);
        acc = __builtin_amdgcn_mfma_f32_16x16x32_bf16(a1, b1, acc, 0, 0, 0);
        int col0 = colbase + ct * 16 + g * 4;
        float4 bias = *(const float4*)(ba + col0);
        if (node < n) {
            float v0 = acc[0] + bias.x, v1 = acc[1] + bias.y;
            float v2 = acc[2] + bias.z, v3 = acc[3] + bias.w;
            if (col0 < 256) {
                ushort4 o;
                o.x = f2h(v0); o.y = f2h(v1); o.z = f2h(v2); o.w = f2h(v3);
                *(ushort4*)(qb + (size_t)node * 256 + col0) = o;
            } else if (col0 < 512) {
                int c = col0 - 256;
#if HAS_FP8
                unsigned pk = __builtin_amdgcn_cvt_pk_fp8_f32(v0, v1, 0u, false);
                pk = __builtin_amdgcn_cvt_pk_fp8_f32(v2, v3, pk, true);
                *(unsigned*)(kb8 + (size_t)node * 256 + c) = pk;
#else
                ushort4 o;
                o.x = f2h(v0); o.y = f2h(v1); o.z = f2h(v2); o.w = f2h(v3);
                *(ushort4*)((u16*)kb8 + (size_t)node * 256 + c) = o;
#endif
            } else if (col0 < 768) {
                int c = col0 - 512;
                ushort4 o;
                o.x = f2h(v0); o.y = f2h(v1); o.z = f2h(v2); o.w = f2h(v3);
                *(ushort4*)(vb + (size_t)node * 256 + c) = o;
            } else {
                ushort4 o;
                o.x = f2h(v0); o.y = f2h(v1); o.z = f2h(v2); o.w = f2h(v3);
                *(ushort4*)(skip + (size_t)node * 64 + (col0 - 768)) = o;
            }
        }
        a0 = an0; a1 = an1;
    }
}

// gemm1 fused with degree histogram (both depend only on prep_misc)
__global__ __launch_bounds__(256) void gemm1_hist(
    const float* __restrict__ x, const u16* __restrict__ wt,
    const float* __restrict__ ba,
    u16* __restrict__ qb, u8* __restrict__ kb8, u16* __restrict__ vb,
    u16* __restrict__ skip, int n,
    const int* __restrict__ dst, int* __restrict__ deg, int E, int gb)
{
    int b = blockIdx.x;
    if (b < gb) {
        gemm_body<1>(b, x, wt, ba, qb, kb8, vb, skip, n);
    } else {
        int e = (b - gb) * 256 + threadIdx.x;
        if (e < E) atomicAdd(&deg[dst[e]], 1);
    }
}

__global__ __launch_bounds__(256) void gemm_qkvs2(
    const u16* __restrict__ xbf, const u16* __restrict__ wt,
    const float* __restrict__ ba,
    u16* __restrict__ qb, u8* __restrict__ kb8, u16* __restrict__ vb,
    u16* __restrict__ skip, int n)
{
    gemm_body<0>(blockIdx.x, xbf, wt, ba, qb, kb8, vb, skip, n);
}

// ---------------------------------------------------------------------------
// Fused attention: ONE node per wave, TWO edge-streams (half-wave each,
// edges t = 2i+half). fp8 k (8B/lane), f16 v (16B/lane), defer-max (THR=8).
// HAND MODULO-SCHEDULED 3-slot pipeline: PROCESS(slot, i) then reload the
// freed slot for i+3 -- no ring-rotation movs. Clamped indices (tail
// re-reads csr[s1-1], cache-hot, masked).
// FINAL: fuse LayerNorm output through LDS into the 64->32 matvec (d_out).
// ---------------------------------------------------------------------------
template <int RELU, int BF16OUT, int FINAL>
__global__ __launch_bounds__(256) void fused_attn(
    const u16* __restrict__ qb, const u8* __restrict__ kb8,
    const u16* __restrict__ vb, const u16* __restrict__ skip,
    const int* __restrict__ off, const int* __restrict__ csr,
    const float* __restrict__ lng, const float* __restrict__ lnb,
    u16* __restrict__ out_bf,
    const float* __restrict__ Wf, const float* __restrict__ bfv,
    float* __restrict__ outF, int n)
{
    const int lane = threadIdx.x & 63;
    const int half = lane >> 5;          // edge-stream parity
    const int hl   = lane & 31;          // h*8 + c8
    const int c8   = lane & 7;
    const int wv   = threadIdx.x >> 6;
    const int node = blockIdx.x * 4 + wv;
    const bool nvalid = node < n;
    const int nodeC = nvalid ? node : n - 1;

    // q: decode f16 row slice to f32 (1/sqrt(C) pre-folded into Wq)
    const int4 qw = *(const int4*)(qb + (size_t)nodeC * 256 + hl * 8);
    float qf[8];
    {
        f16x2 t0 = u2h(qw.x), t1 = u2h(qw.y), t2 = u2h(qw.z), t3 = u2h(qw.w);
        qf[0] = (float)t0.x; qf[1] = (float)t0.y;
        qf[2] = (float)t1.x; qf[3] = (float)t1.y;
        qf[4] = (float)t2.x; qf[5] = (float)t2.y;
        qf[6] = (float)t3.x; qf[7] = (float)t3.y;
    }

    const int s0 = off[nodeC], s1 = off[nodeC + 1];
    const int deg = nvalid ? (s1 - s0) : 0;
    const int imax = (deg + 1) >> 1;     // iterations per stream

    float m = -1e30f, l = 0.f;
    float a[8] = {0.f, 0.f, 0.f, 0.f, 0.f, 0.f, 0.f, 0.f};

    if (imax > 0) {
#if HAS_FP8
        const u8* kbase = kb8 + hl * 8;
#else
        const u16* kbase = (const u16*)kb8 + hl * 8;
#endif
        const u16* vbase = vb + hl * 8;
        const int* cp = csr + s0 + half;
        const int dclamp = deg - 1 - half;   // cp[dclamp] == csr[s1-1]

        #define LOADKV(I, K, V) { \
            int _o = min(2 * (I), dclamp); \
            int _s = cp[_o]; \
            K = *(const kreg_t*)(kbase + (size_t)_s * 256); \
            V = *(const int4*)(vbase + (size_t)_s * 256); }

        #define PROCESS(K, V, I) { \
            float p = dotqk(K, qf); \
            p += __shfl_xor(p, 1); \
            p += __shfl_xor(p, 2); \
            p += __shfl_xor(p, 4); \
            p = (2 * (I) + half < deg) ? p : -2e30f; \
            f16x2 w0 = u2h(V.x), w1 = u2h(V.y), w2 = u2h(V.z), w3 = u2h(V.w); \
            if (__all(p - m <= 8.f)) { \
                float e = __expf(p - m); l += e; \
                a[0] = fmaf(e, (float)w0.x, a[0]); a[1] = fmaf(e, (float)w0.y, a[1]); \
                a[2] = fmaf(e, (float)w1.x, a[2]); a[3] = fmaf(e, (float)w1.y, a[3]); \
                a[4] = fmaf(e, (float)w2.x, a[4]); a[5] = fmaf(e, (float)w2.y, a[5]); \
                a[6] = fmaf(e, (float)w3.x, a[6]); a[7] = fmaf(e, (float)w3.y, a[7]); \
            } else { \
                float nm = fmaxf(m, p); \
                float c = __expf(m - nm); \
                float e = __expf(p - nm); \
                m = nm; l = l * c + e; \
                a[0] = fmaf(e, (float)w0.x, a[0] * c); a[1] = fmaf(e, (float)w0.y, a[1] * c); \
                a[2] = fmaf(e, (float)w1.x, a[2] * c); a[3] = fmaf(e, (float)w1.y, a[3] * c); \
                a[4] = fmaf(e, (float)w2.x, a[4] * c); a[5] = fmaf(e, (float)w2.y, a[5] * c); \
                a[6] = fmaf(e, (float)w3.x, a[6] * c); a[7] = fmaf(e, (float)w3.y, a[7] * c); \
            } }

        kreg_t kA, kB, kC;
        int4 vA, vB, vC;
        LOADKV(0, kA, vA);
        LOADKV(1, kB, vB);
        LOADKV(2, kC, vC);

        int i = 0;
        for (; i + 3 <= imax; i += 3) {
            PROCESS(kA, vA, i);     LOADKV(i + 3, kA, vA);
            PROCESS(kB, vB, i + 1); LOADKV(i + 4, kB, vB);
            PROCESS(kC, vC, i + 2); LOADKV(i + 5, kC, vC);
        }
        if (i < imax)     PROCESS(kA, vA, i);
        if (i + 1 < imax) PROCESS(kB, vB, i + 1);

        #undef LOADKV
        #undef PROCESS
    }

    // merge the two streams (lane ^ 32 holds the partner state)
    {
        float mo = __shfl_xor(m, 32);
        float lo_ = __shfl_xor(l, 32);
        float nm = fmaxf(m, mo);
        float c  = __expf(m - nm);
        float co = __expf(mo - nm);
        l = l * c + lo_ * co;
        #pragma unroll
        for (int j = 0; j < 8; ++j) {
            float ao = __shfl_xor(a[j], 32);
            a[j] = a[j] * c + ao * co;
        }
    }

    // normalize per head, then mean over heads (hl bits 3,4)
    const float inv = 0.25f / (l + 1e-16f);
    #pragma unroll
    for (int j = 0; j < 8; ++j) {
        a[j] *= inv;
        a[j] += __shfl_xor(a[j], 8);
        a[j] += __shfl_xor(a[j], 16);
    }

    // skip connection (f16): channels c8*8 .. +7
    const int4 skw = *(const int4*)(skip + (size_t)nodeC * 64 + c8 * 8);
    f16x2 s0_ = u2h(skw.x), s1_ = u2h(skw.y), s2_ = u2h(skw.z), s3_ = u2h(skw.w);
    float o[8];
    o[0] = a[0] + (float)s0_.x; o[1] = a[1] + (float)s0_.y;
    o[2] = a[2] + (float)s1_.x; o[3] = a[3] + (float)s1_.y;
    o[4] = a[4] + (float)s2_.x; o[5] = a[5] + (float)s2_.y;
    o[6] = a[6] + (float)s3_.x; o[7] = a[7] + (float)s3_.y;

    // LayerNorm over 64 channels (8 lanes x 8 ch within each 8-lane group)
    float s = o[0] + o[1] + o[2] + o[3] + o[4] + o[5] + o[6] + o[7];
    s += __shfl_xor(s, 1); s += __shfl_xor(s, 2); s += __shfl_xor(s, 4);
    const float mu = s * (1.f / 64.f);
    float vs = 0.f;
    #pragma unroll
    for (int j = 0; j < 8; ++j) { o[j] -= mu; vs = fmaf(o[j], o[j], vs); }
    vs += __shfl_xor(vs, 1); vs += __shfl_xor(vs, 2); vs += __shfl_xor(vs, 4);
    const float rs = rsqrtf(vs * (1.f / 64.f) + 1e-5f);

    const float4* gp = (const float4*)(lng + c8 * 8);
    const float4* bp = (const float4*)(lnb + c8 * 8);
    float4 g0 = gp[0], g1 = gp[1], b0 = bp[0], b1 = bp[1];
    float y[8];
    y[0] = o[0] * rs * g0.x + b0.x; y[1] = o[1] * rs * g0.y + b0.y;
    y[2] = o[2] * rs * g0.z + b0.z; y[3] = o[3] * rs * g0.w + b0.w;
    y[4] = o[4] * rs * g1.x + b1.x; y[5] = o[5] * rs * g1.y + b1.y;
    y[6] = o[6] * rs * g1.z + b1.z; y[7] = o[7] * rs * g1.w + b1.w;
    if (RELU) {
        #pragma unroll
        for (int j = 0; j < 8; ++j) y[j] = fmaxf(y[j], 0.f);
    }

    if (FINAL) {
        // fused 64->32 matvec via LDS (y of 4 nodes staged per block)
        __shared__ float yl[4][64];
        if (lane < 8) {
            #pragma unroll
            for (int j = 0; j < 8; ++j) yl[wv][c8 * 8 + j] = y[j];
        }
        __syncthreads();
        int t = threadIdx.x;
        if (t < 128) {
            int nd = t >> 5, oc = t & 31;
            int gn = blockIdx.x * 4 + nd;
            if (gn < n) {
                float acc = bfv[oc];
                #pragma unroll
                for (int c = 0; c < 64; ++c)
                    acc = fmaf(yl[nd][c], Wf[c * 32 + oc], acc);
                outF[(size_t)gn * 32 + oc] = acc;
            }
        }
    } else if (lane < 8 && nvalid) {
        if (BF16OUT) {
            bf16x8 ob;
            #pragma unroll
            for (int j = 0; j < 8; ++j) ob[j] = (short)f2bf(y[j]);
            *(bf16x8*)(out_bf + (size_t)node * 64 + c8 * 8) = ob;
        }
    }
}

// ---------------------------------------------------------------------------
extern "C" void kernel_launch(void* const* d_in, const int* in_sizes, int n_in,
                              void* d_out, int out_size, void* d_ws, size_t ws_size,
                              hipStream_t stream)
{
    const float* x   = (const float*)d_in[0];
    const int*   ei  = (const int*)d_in[1];
    const float* Wq1 = (const float*)d_in[2];  const float* bq1 = (const float*)d_in[3];
    const float* Wk1 = (const float*)d_in[4];  const float* bk1 = (const float*)d_in[5];
    const float* Wv1 = (const float*)d_in[6];  const float* bv1 = (const float*)d_in[7];
    const float* Ws1 = (const float*)d_in[8];  const float* bs1 = (const float*)d_in[9];
    const float* Wq2 = (const float*)d_in[10]; const float* bq2 = (const float*)d_in[11];
    const float* Wk2 = (const float*)d_in[12]; const float* bk2 = (const float*)d_in[13];
    const float* Wv2 = (const float*)d_in[14]; const float* bv2 = (const float*)d_in[15];
    const float* Ws2 = (const float*)d_in[16]; const float* bs2 = (const float*)d_in[17];
    const float* lng = (const float*)d_in[18]; const float* lnb = (const float*)d_in[19];
    const float* Wf  = (const float*)d_in[20]; const float* bf  = (const float*)d_in[21];

    const int N = in_sizes[0] / 64;
    const int E = in_sizes[1] / 2;
    const int* src  = ei;
    const int* dstp = ei + E;

    char* p = (char*)d_ws;
    u16* qb   = (u16*)p; p += (size_t)N * 256 * 2;   // f16
    u8*  kb8  = (u8*)p;  p += (size_t)N * 256 * 2;   // fp8 (f16 fallback fits)
    u16* vb   = (u16*)p; p += (size_t)N * 256 * 2;   // f16
    u16* xbf  = (u16*)p; p += (size_t)N * 64 * 2;    // conv1 output h (bf16)
    u16* wt1  = (u16*)p; p += 832 * 64 * 2;
    u16* wt2  = (u16*)p; p += 832 * 64 * 2;
    float* ba1  = (float*)p; p += 832 * 4;
    float* ba2  = (float*)p; p += 832 * 4;
    u16* skip = (u16*)p; p += (size_t)N * 64 * 2;    // f16
    int* deg    = (int*)p; p += (size_t)N * 4;
    int* off    = (int*)p; p += ((size_t)N + 1) * 4;
    int* cursor = (int*)p; p += (size_t)N * 4;
    int* csr    = (int*)p; p += (size_t)E * 4;
    int* bsum   = (int*)p; p += 1024;
    int* bpre   = (int*)p; p += 1024;

    const int e_blocks    = (E + 255) / 256;
    const int n_blocks    = (N + 255) / 256;
    const int prep_blocks = 416 + n_blocks;
    const int gb          = (N + 15) / 16;
    const int attn_blocks = (N + 3) / 4;            // 1 node/wave, 4 waves/blk

    // ---- prep: fused conversions + zero deg ----
    prep_misc<<<prep_blocks, 256, 0, stream>>>(
        Wq1, Wk1, Wv1, Ws1, bq1, bk1, bv1, bs1,
        Wq2, Wk2, Wv2, Ws2, bq2, bk2, bv2, bs2,
        wt1, ba1, wt2, ba2, deg, N);

    // ---- conv1 GEMM + degree histogram (fused, both only need prep) ----
    gemm1_hist<<<gb + e_blocks, 256, 0, stream>>>(
        x, wt1, ba1, qb, kb8, vb, skip, N, dstp, deg, E, gb);

    // ---- CSR scan + fill ----
    scanA<<<n_blocks, 256, 0, stream>>>(deg, bsum, N);
    scanB<<<1, 256, 0, stream>>>(bsum, bpre, n_blocks);
    scanC<<<n_blocks, 256, 0, stream>>>(deg, bpre, off, cursor, N, E);
    fill_kernel<<<e_blocks, 256, 0, stream>>>(src, dstp, cursor, csr, E);

    // ---- conv1 attention (writes h bf16) ----
    fused_attn<1, 1, 0><<<attn_blocks, 256, 0, stream>>>(
        qb, kb8, vb, skip, off, csr, lng, lnb, xbf, nullptr, nullptr, nullptr, N);

    // ---- conv2 GEMM ----
    gemm_qkvs2<<<gb, 256, 0, stream>>>(xbf, wt2, ba2, qb, kb8, vb, skip, N);

    // ---- conv2 attention + fused final LN/Linear -> d_out ----
    fused_attn<0, 0, 1><<<attn_blocks, 256, 0, stream>>>(
        qb, kb8, vb, skip, off, csr, lng, lnb, nullptr, Wf, bf, (float*)d_out, N);
}

// Round 12
// 405.645 us; speedup vs baseline: 1.0416x; 1.0399x over previous
//
#include <hip/hip_runtime.h>
#include <hip/hip_bf16.h>
#include <math.h>

typedef unsigned short u16;
typedef unsigned char u8;
typedef __attribute__((ext_vector_type(8))) short bf16x8;
typedef __attribute__((ext_vector_type(4))) float f32x4;
typedef __attribute__((ext_vector_type(2))) float f32x2;
typedef _Float16 f16;
typedef __attribute__((ext_vector_type(2))) _Float16 f16x2;

#if __has_builtin(__builtin_amdgcn_cvt_pk_f32_fp8) && __has_builtin(__builtin_amdgcn_cvt_pk_fp8_f32)
#define HAS_FP8 1
#else
#define HAS_FP8 0
#endif

__device__ __forceinline__ u16 f2bf(float f) {
    unsigned u = __float_as_uint(f);
    u += 0x7fffu + ((u >> 16) & 1u);   // RNE
    return (u16)(u >> 16);
}
__device__ __forceinline__ u16 f2h(float f) {
    return __builtin_bit_cast(u16, (f16)f);   // v_cvt_f16_f32 (RNE)
}
__device__ __forceinline__ f16x2 u2h(int u) {
    return __builtin_bit_cast(f16x2, u);
}

#if HAS_FP8
typedef uint2 kreg_t;
__device__ __forceinline__ float dotqk(kreg_t K, const float qf[8]) {
    f32x2 d0 = __builtin_amdgcn_cvt_pk_f32_fp8(K.x, false);
    f32x2 d1 = __builtin_amdgcn_cvt_pk_f32_fp8(K.x, true);
    f32x2 d2 = __builtin_amdgcn_cvt_pk_f32_fp8(K.y, false);
    f32x2 d3 = __builtin_amdgcn_cvt_pk_f32_fp8(K.y, true);
    float p = d0.x * qf[0];
    p = fmaf(d0.y, qf[1], p); p = fmaf(d1.x, qf[2], p); p = fmaf(d1.y, qf[3], p);
    p = fmaf(d2.x, qf[4], p); p = fmaf(d2.y, qf[5], p);
    p = fmaf(d3.x, qf[6], p); p = fmaf(d3.y, qf[7], p);
    return p;
}
#else
typedef int4 kreg_t;
__device__ __forceinline__ float dotqk(kreg_t K, const float qf[8]) {
    f16x2 t0 = u2h(K.x), t1 = u2h(K.y), t2 = u2h(K.z), t3 = u2h(K.w);
    float p = (float)t0.x * qf[0];
    p = fmaf((float)t0.y, qf[1], p); p = fmaf((float)t1.x, qf[2], p);
    p = fmaf((float)t1.y, qf[3], p); p = fmaf((float)t2.x, qf[4], p);
    p = fmaf((float)t2.y, qf[5], p); p = fmaf((float)t3.x, qf[6], p);
    p = fmaf((float)t3.y, qf[7], p);
    return p;
}
#endif

// ---------------------------------------------------------------------------
// prep_misc: grid-partitioned fusion of {convert W1, convert W2, zero deg}.
// wt[832][64] bf16 (cols 0-255 q *0.125 folded, 256-511 k, 512-767 v,
// 768-831 s), bias ba[832] fp32 (q part *0.125).
// ---------------------------------------------------------------------------
__device__ __forceinline__ void conv_w_one(
    int idx,
    const float* __restrict__ Wq, const float* __restrict__ Wk,
    const float* __restrict__ Wv, const float* __restrict__ Ws,
    const float* __restrict__ bq, const float* __restrict__ bk,
    const float* __restrict__ bv, const float* __restrict__ bs,
    u16* __restrict__ wt, float* __restrict__ ba)
{
    int col = idx >> 6, k = idx & 63;
    float w;
    if      (col < 256) w = Wq[k * 256 + col] * 0.125f;          // fold 1/sqrt(C)
    else if (col < 512) w = Wk[k * 256 + (col - 256)];
    else if (col < 768) w = Wv[k * 256 + (col - 512)];
    else                w = Ws[k * 64  + (col - 768)];
    wt[col * 64 + k] = f2bf(w);
    if (k == 0)
        ba[col] = (col < 256) ? bq[col] * 0.125f : (col < 512) ? bk[col - 256]
                 : (col < 768) ? bv[col - 512] : bs[col - 768];
}

__global__ __launch_bounds__(256) void prep_misc(
    const float* __restrict__ Wq1, const float* __restrict__ Wk1,
    const float* __restrict__ Wv1, const float* __restrict__ Ws1,
    const float* __restrict__ bq1, const float* __restrict__ bk1,
    const float* __restrict__ bv1, const float* __restrict__ bs1,
    const float* __restrict__ Wq2, const float* __restrict__ Wk2,
    const float* __restrict__ Wv2, const float* __restrict__ Ws2,
    const float* __restrict__ bq2, const float* __restrict__ bk2,
    const float* __restrict__ bv2, const float* __restrict__ bs2,
    u16* __restrict__ wt1, float* __restrict__ ba1,
    u16* __restrict__ wt2, float* __restrict__ ba2,
    int* __restrict__ deg, int n)
{
    int b = blockIdx.x, t = threadIdx.x;
    if (b < 208) {
        conv_w_one(b * 256 + t, Wq1, Wk1, Wv1, Ws1, bq1, bk1, bv1, bs1, wt1, ba1);
    } else if (b < 416) {
        conv_w_one((b - 208) * 256 + t, Wq2, Wk2, Wv2, Ws2, bq2, bk2, bv2, bs2, wt2, ba2);
    } else {
        int i = (b - 416) * 256 + t;
        if (i < n) deg[i] = 0;
    }
}

// ---------------------------------------------------------------------------
// CSR scan (3-phase coalesced) + fill
// ---------------------------------------------------------------------------
__global__ __launch_bounds__(256) void scanA(
    const int* __restrict__ deg, int* __restrict__ bsum, int n)
{
    int i = blockIdx.x * 256 + threadIdx.x;
    int v = (i < n) ? deg[i] : 0;
    #pragma unroll
    for (int o = 32; o; o >>= 1) v += __shfl_xor(v, o);
    __shared__ int wsum[4];
    if ((threadIdx.x & 63) == 0) wsum[threadIdx.x >> 6] = v;
    __syncthreads();
    if (threadIdx.x == 0)
        bsum[blockIdx.x] = wsum[0] + wsum[1] + wsum[2] + wsum[3];
}

__global__ __launch_bounds__(256) void scanB(
    const int* __restrict__ bsum, int* __restrict__ bpre, int nb)
{
    int t = threadIdx.x;
    int v = (t < nb) ? bsum[t] : 0;
    int lane = t & 63, wv = t >> 6;
    int sv = v;
    #pragma unroll
    for (int o = 1; o < 64; o <<= 1) {
        int u = __shfl_up(sv, o);
        if (lane >= o) sv += u;
    }
    __shared__ int wsum[4];
    if (lane == 63) wsum[wv] = sv;
    __syncthreads();
    int add = 0;
    for (int k = 0; k < wv; ++k) add += wsum[k];
    if (t < nb) bpre[t] = sv + add - v;   // exclusive
}

__global__ __launch_bounds__(256) void scanC(
    const int* __restrict__ deg, const int* __restrict__ bpre,
    int* __restrict__ off, int* __restrict__ cursor, int n, int E)
{
    int i = blockIdx.x * 256 + threadIdx.x;
    int v = (i < n) ? deg[i] : 0;
    int lane = threadIdx.x & 63, wv = threadIdx.x >> 6;
    int sv = v;
    #pragma unroll
    for (int o = 1; o < 64; o <<= 1) {
        int u = __shfl_up(sv, o);
        if (lane >= o) sv += u;
    }
    __shared__ int wsum[4];
    if (lane == 63) wsum[wv] = sv;
    __syncthreads();
    int add = bpre[blockIdx.x];
    for (int k = 0; k < wv; ++k) add += wsum[k];
    int excl = add + sv - v;
    if (i < n) {
        off[i] = excl; cursor[i] = excl;
        if (i == n - 1) off[n] = E;
    }
}

__global__ __launch_bounds__(256) void fill_kernel(
    const int* __restrict__ src, const int* __restrict__ dst,
    int* __restrict__ cursor, int* __restrict__ csr_src, int E)
{
    int e = blockIdx.x * 256 + threadIdx.x;
    if (e >= E) return;
    int slot = atomicAdd(&cursor[dst[e]], 1);
    csr_src[slot] = src[e];
}

// ---------------------------------------------------------------------------
// bf16 MFMA GEMM body (device fn). W as A-operand / X as B-operand; each
// lane owns 4 consecutive output cols of one node. q/v f16, k fp8, skip f16.
// ---------------------------------------------------------------------------
template <int FP32IN>
__device__ __forceinline__ void gemm_body(
    int blk, const void* __restrict__ Xv, const u16* __restrict__ wt,
    const float* __restrict__ ba,
    u16* __restrict__ qb, u8* __restrict__ kb8, u16* __restrict__ vb,
    u16* __restrict__ skip, int n)
{
    const int w = threadIdx.x >> 6, lane = threadIdx.x & 63;
    const int r = lane & 15, g = lane >> 4;
    const int node0 = blk * 16;

    int nr = node0 + r; if (nr >= n) nr = n - 1;
    bf16x8 b0, b1;                            // X fragment (B operand)
    if (FP32IN) {
        const float* xr = (const float*)Xv + (size_t)nr * 64 + g * 8;
        float t0[8], t1[8];
        *(float4*)(t0)     = ((const float4*)xr)[0];
        *(float4*)(t0 + 4) = ((const float4*)xr)[1];
        *(float4*)(t1)     = ((const float4*)(xr + 32))[0];
        *(float4*)(t1 + 4) = ((const float4*)(xr + 32))[1];
        #pragma unroll
        for (int j = 0; j < 8; ++j) {
            b0[j] = (short)f2bf(t0[j]);
            b1[j] = (short)f2bf(t1[j]);
        }
    } else {
        const u16* xr = (const u16*)Xv + (size_t)nr * 64 + g * 8;
        b0 = *(const bf16x8*)xr;
        b1 = *(const bf16x8*)(xr + 32);
    }

    const int colbase = w * 208;
    const int node = node0 + r;

    const u16* wr0 = wt + (size_t)(colbase + r) * 64 + g * 8;
    bf16x8 a0 = *(const bf16x8*)wr0;
    bf16x8 a1 = *(const bf16x8*)(wr0 + 32);

    for (int ct = 0; ct < 13; ++ct) {
        int ctn = (ct + 1 < 13) ? ct + 1 : 12;
        const u16* wrn = wt + (size_t)(colbase + ctn * 16 + r) * 64 + g * 8;
        bf16x8 an0 = *(const bf16x8*)wrn;
        bf16x8 an1 = *(const bf16x8*)(wrn + 32);

        f32x4 acc = {0.f, 0.f, 0.f, 0.f};
        acc = __builtin_amdgcn_mfma_f32_16x16x32_bf16(a0, b0, acc, 0, 0, 0);
        acc = __builtin_amdgcn_mfma_f32_16x16x32_bf16(a1, b1, acc, 0, 0, 0);
        int col0 = colbase + ct * 16 + g * 4;
        float4 bias = *(const float4*)(ba + col0);
        if (node < n) {
            float v0 = acc[0] + bias.x, v1 = acc[1] + bias.y;
            float v2 = acc[2] + bias.z, v3 = acc[3] + bias.w;
            if (col0 < 256) {
                ushort4 o;
                o.x = f2h(v0); o.y = f2h(v1); o.z = f2h(v2); o.w = f2h(v3);
                *(ushort4*)(qb + (size_t)node * 256 + col0) = o;
            } else if (col0 < 512) {
                int c = col0 - 256;
#if HAS_FP8
                unsigned pk = __builtin_amdgcn_cvt_pk_fp8_f32(v0, v1, 0u, false);
                pk = __builtin_amdgcn_cvt_pk_fp8_f32(v2, v3, pk, true);
                *(unsigned*)(kb8 + (size_t)node * 256 + c) = pk;
#else
                ushort4 o;
                o.x = f2h(v0); o.y = f2h(v1); o.z = f2h(v2); o.w = f2h(v3);
                *(ushort4*)((u16*)kb8 + (size_t)node * 256 + c) = o;
#endif
            } else if (col0 < 768) {
                int c = col0 - 512;
                ushort4 o;
                o.x = f2h(v0); o.y = f2h(v1); o.z = f2h(v2); o.w = f2h(v3);
                *(ushort4*)(vb + (size_t)node * 256 + c) = o;
            } else {
                ushort4 o;
                o.x = f2h(v0); o.y = f2h(v1); o.z = f2h(v2); o.w = f2h(v3);
                *(ushort4*)(skip + (size_t)node * 64 + (col0 - 768)) = o;
            }
        }
        a0 = an0; a1 = an1;
    }
}

// gemm1 fused with degree histogram (both depend only on prep_misc)
__global__ __launch_bounds__(256) void gemm1_hist(
    const float* __restrict__ x, const u16* __restrict__ wt,
    const float* __restrict__ ba,
    u16* __restrict__ qb, u8* __restrict__ kb8, u16* __restrict__ vb,
    u16* __restrict__ skip, int n,
    const int* __restrict__ dst, int* __restrict__ deg, int E, int gb)
{
    int b = blockIdx.x;
    if (b < gb) {
        gemm_body<1>(b, x, wt, ba, qb, kb8, vb, skip, n);
    } else {
        int e = (b - gb) * 256 + threadIdx.x;
        if (e < E) atomicAdd(&deg[dst[e]], 1);
    }
}

__global__ __launch_bounds__(256) void gemm_qkvs2(
    const u16* __restrict__ xbf, const u16* __restrict__ wt,
    const float* __restrict__ ba,
    u16* __restrict__ qb, u8* __restrict__ kb8, u16* __restrict__ vb,
    u16* __restrict__ skip, int n)
{
    gemm_body<0>(blockIdx.x, xbf, wt, ba, qb, kb8, vb, skip, n);
}

// ---------------------------------------------------------------------------
// Fused attention: ONE node per wave, TWO edge-streams (half-wave each,
// edges t = 2i+half). fp8 k (8B/lane), f16 v (16B/lane), defer-max (THR=8),
// clamped 3-deep prefetch ring under #pragma unroll 3 (R10 structure —
// compiler renames the rotation; 40 VGPR / 53% occupancy proven).
// FINAL: fuse LayerNorm output through LDS into the 64->32 matvec (d_out).
// ---------------------------------------------------------------------------
template <int RELU, int BF16OUT, int FINAL>
__global__ __launch_bounds__(256) void fused_attn(
    const u16* __restrict__ qb, const u8* __restrict__ kb8,
    const u16* __restrict__ vb, const u16* __restrict__ skip,
    const int* __restrict__ off, const int* __restrict__ csr,
    const float* __restrict__ lng, const float* __restrict__ lnb,
    u16* __restrict__ out_bf,
    const float* __restrict__ Wf, const float* __restrict__ bfv,
    float* __restrict__ outF, int n)
{
    const int lane = threadIdx.x & 63;
    const int half = lane >> 5;          // edge-stream parity
    const int hl   = lane & 31;          // h*8 + c8
    const int c8   = lane & 7;
    const int wv   = threadIdx.x >> 6;
    const int node = blockIdx.x * 4 + wv;
    const bool nvalid = node < n;
    const int nodeC = nvalid ? node : n - 1;

    // q: decode f16 row slice to f32 (1/sqrt(C) pre-folded into Wq)
    const int4 qw = *(const int4*)(qb + (size_t)nodeC * 256 + hl * 8);
    float qf[8];
    {
        f16x2 t0 = u2h(qw.x), t1 = u2h(qw.y), t2 = u2h(qw.z), t3 = u2h(qw.w);
        qf[0] = (float)t0.x; qf[1] = (float)t0.y;
        qf[2] = (float)t1.x; qf[3] = (float)t1.y;
        qf[4] = (float)t2.x; qf[5] = (float)t2.y;
        qf[6] = (float)t3.x; qf[7] = (float)t3.y;
    }

    const int s0 = off[nodeC], s1 = off[nodeC + 1];
    const int deg = nvalid ? (s1 - s0) : 0;
    const int imax = (deg + 1) >> 1;     // iterations per stream

    float m = -1e30f, l = 0.f;
    float a[8] = {0.f, 0.f, 0.f, 0.f, 0.f, 0.f, 0.f, 0.f};

    if (imax > 0) {
#if HAS_FP8
        const u8* kbase = kb8 + hl * 8;
#else
        const u16* kbase = (const u16*)kb8 + hl * 8;
#endif
        const u16* vbase = vb + hl * 8;
        // clamped: tail loads re-read row csr[s1-1] (cache-hot, masked out)
        #define LOADKV(I, K, V) { \
            int _ix = min(s0 + 2 * (I) + half, s1 - 1); \
            int _s = csr[_ix]; \
            K = *(const kreg_t*)(kbase + (size_t)_s * 256); \
            V = *(const int4*)(vbase + (size_t)_s * 256); }

        kreg_t k0, k1, k2;
        int4 v0, v1, v2;
        LOADKV(0, k0, v0);
        LOADKV(1, k1, v1);
        LOADKV(2, k2, v2);

        #pragma unroll 3
        for (int i = 0; i < imax; ++i) {
            kreg_t kn; int4 vn;
            LOADKV(i + 3, kn, vn);

            float p = dotqk(k0, qf);
            p += __shfl_xor(p, 1);
            p += __shfl_xor(p, 2);
            p += __shfl_xor(p, 4);
            p = (2 * i + half < deg) ? p : -2e30f;   // tail mask

            f16x2 va0 = u2h(v0.x), va1 = u2h(v0.y);
            f16x2 va2 = u2h(v0.z), va3 = u2h(v0.w);
            if (__all(p - m <= 8.f)) {
                // defer-max fast path: no rescale (P bounded by e^8)
                float e = __expf(p - m);
                l += e;
                a[0] = fmaf(e, (float)va0.x, a[0]);
                a[1] = fmaf(e, (float)va0.y, a[1]);
                a[2] = fmaf(e, (float)va1.x, a[2]);
                a[3] = fmaf(e, (float)va1.y, a[3]);
                a[4] = fmaf(e, (float)va2.x, a[4]);
                a[5] = fmaf(e, (float)va2.y, a[5]);
                a[6] = fmaf(e, (float)va3.x, a[6]);
                a[7] = fmaf(e, (float)va3.y, a[7]);
            } else {
                float nm = fmaxf(m, p);
                float c = __expf(m - nm);
                float e = __expf(p - nm);
                m = nm;
                l = l * c + e;
                a[0] = fmaf(e, (float)va0.x, a[0] * c);
                a[1] = fmaf(e, (float)va0.y, a[1] * c);
                a[2] = fmaf(e, (float)va1.x, a[2] * c);
                a[3] = fmaf(e, (float)va1.y, a[3] * c);
                a[4] = fmaf(e, (float)va2.x, a[4] * c);
                a[5] = fmaf(e, (float)va2.y, a[5] * c);
                a[6] = fmaf(e, (float)va3.x, a[6] * c);
                a[7] = fmaf(e, (float)va3.y, a[7] * c);
            }

            k0 = k1; v0 = v1; k1 = k2; v1 = v2; k2 = kn; v2 = vn;
        }
        #undef LOADKV
    }

    // merge the two streams (lane ^ 32 holds the partner state)
    {
        float mo = __shfl_xor(m, 32);
        float lo_ = __shfl_xor(l, 32);
        float nm = fmaxf(m, mo);
        float c  = __expf(m - nm);
        float co = __expf(mo - nm);
        l = l * c + lo_ * co;
        #pragma unroll
        for (int j = 0; j < 8; ++j) {
            float ao = __shfl_xor(a[j], 32);
            a[j] = a[j] * c + ao * co;
        }
    }

    // normalize per head, then mean over heads (hl bits 3,4)
    const float inv = 0.25f / (l + 1e-16f);
    #pragma unroll
    for (int j = 0; j < 8; ++j) {
        a[j] *= inv;
        a[j] += __shfl_xor(a[j], 8);
        a[j] += __shfl_xor(a[j], 16);
    }

    // skip connection (f16): channels c8*8 .. +7
    const int4 skw = *(const int4*)(skip + (size_t)nodeC * 64 + c8 * 8);
    f16x2 s0_ = u2h(skw.x), s1_ = u2h(skw.y), s2_ = u2h(skw.z), s3_ = u2h(skw.w);
    float o[8];
    o[0] = a[0] + (float)s0_.x; o[1] = a[1] + (float)s0_.y;
    o[2] = a[2] + (float)s1_.x; o[3] = a[3] + (float)s1_.y;
    o[4] = a[4] + (float)s2_.x; o[5] = a[5] + (float)s2_.y;
    o[6] = a[6] + (float)s3_.x; o[7] = a[7] + (float)s3_.y;

    // LayerNorm over 64 channels (8 lanes x 8 ch within each 8-lane group)
    float s = o[0] + o[1] + o[2] + o[3] + o[4] + o[5] + o[6] + o[7];
    s += __shfl_xor(s, 1); s += __shfl_xor(s, 2); s += __shfl_xor(s, 4);
    const float mu = s * (1.f / 64.f);
    float vs = 0.f;
    #pragma unroll
    for (int j = 0; j < 8; ++j) { o[j] -= mu; vs = fmaf(o[j], o[j], vs); }
    vs += __shfl_xor(vs, 1); vs += __shfl_xor(vs, 2); vs += __shfl_xor(vs, 4);
    const float rs = rsqrtf(vs * (1.f / 64.f) + 1e-5f);

    const float4* gp = (const float4*)(lng + c8 * 8);
    const float4* bp = (const float4*)(lnb + c8 * 8);
    float4 g0 = gp[0], g1 = gp[1], b0 = bp[0], b1 = bp[1];
    float y[8];
    y[0] = o[0] * rs * g0.x + b0.x; y[1] = o[1] * rs * g0.y + b0.y;
    y[2] = o[2] * rs * g0.z + b0.z; y[3] = o[3] * rs * g0.w + b0.w;
    y[4] = o[4] * rs * g1.x + b1.x; y[5] = o[5] * rs * g1.y + b1.y;
    y[6] = o[6] * rs * g1.z + b1.z; y[7] = o[7] * rs * g1.w + b1.w;
    if (RELU) {
        #pragma unroll
        for (int j = 0; j < 8; ++j) y[j] = fmaxf(y[j], 0.f);
    }

    if (FINAL) {
        // fused 64->32 matvec via LDS (y of 4 nodes staged per block)
        __shared__ float yl[4][64];
        if (lane < 8) {
            #pragma unroll
            for (int j = 0; j < 8; ++j) yl[wv][c8 * 8 + j] = y[j];
        }
        __syncthreads();
        int t = threadIdx.x;
        if (t < 128) {
            int nd = t >> 5, oc = t & 31;
            int gn = blockIdx.x * 4 + nd;
            if (gn < n) {
                float acc = bfv[oc];
                #pragma unroll
                for (int c = 0; c < 64; ++c)
                    acc = fmaf(yl[nd][c], Wf[c * 32 + oc], acc);
                outF[(size_t)gn * 32 + oc] = acc;
            }
        }
    } else if (lane < 8 && nvalid) {
        if (BF16OUT) {
            bf16x8 ob;
            #pragma unroll
            for (int j = 0; j < 8; ++j) ob[j] = (short)f2bf(y[j]);
            *(bf16x8*)(out_bf + (size_t)node * 64 + c8 * 8) = ob;
        }
    }
}

// ---------------------------------------------------------------------------
extern "C" void kernel_launch(void* const* d_in, const int* in_sizes, int n_in,
                              void* d_out, int out_size, void* d_ws, size_t ws_size,
                              hipStream_t stream)
{
    const float* x   = (const float*)d_in[0];
    const int*   ei  = (const int*)d_in[1];
    const float* Wq1 = (const float*)d_in[2];  const float* bq1 = (const float*)d_in[3];
    const float* Wk1 = (const float*)d_in[4];  const float* bk1 = (const float*)d_in[5];
    const float* Wv1 = (const float*)d_in[6];  const float* bv1 = (const float*)d_in[7];
    const float* Ws1 = (const float*)d_in[8];  const float* bs1 = (const float*)d_in[9];
    const float* Wq2 = (const float*)d_in[10]; const float* bq2 = (const float*)d_in[11];
    const float* Wk2 = (const float*)d_in[12]; const float* bk2 = (const float*)d_in[13];
    const float* Wv2 = (const float*)d_in[14]; const float* bv2 = (const float*)d_in[15];
    const float* Ws2 = (const float*)d_in[16]; const float* bs2 = (const float*)d_in[17];
    const float* lng = (const float*)d_in[18]; const float* lnb = (const float*)d_in[19];
    const float* Wf  = (const float*)d_in[20]; const float* bf  = (const float*)d_in[21];

    const int N = in_sizes[0] / 64;
    const int E = in_sizes[1] / 2;
    const int* src  = ei;
    const int* dstp = ei + E;

    char* p = (char*)d_ws;
    u16* qb   = (u16*)p; p += (size_t)N * 256 * 2;   // f16
    u8*  kb8  = (u8*)p;  p += (size_t)N * 256 * 2;   // fp8 (f16 fallback fits)
    u16* vb   = (u16*)p; p += (size_t)N * 256 * 2;   // f16
    u16* xbf  = (u16*)p; p += (size_t)N * 64 * 2;    // conv1 output h (bf16)
    u16* wt1  = (u16*)p; p += 832 * 64 * 2;
    u16* wt2  = (u16*)p; p += 832 * 64 * 2;
    float* ba1  = (float*)p; p += 832 * 4;
    float* ba2  = (float*)p; p += 832 * 4;
    u16* skip = (u16*)p; p += (size_t)N * 64 * 2;    // f16
    int* deg    = (int*)p; p += (size_t)N * 4;
    int* off    = (int*)p; p += ((size_t)N + 1) * 4;
    int* cursor = (int*)p; p += (size_t)N * 4;
    int* csr    = (int*)p; p += (size_t)E * 4;
    int* bsum   = (int*)p; p += 1024;
    int* bpre   = (int*)p; p += 1024;

    const int e_blocks    = (E + 255) / 256;
    const int n_blocks    = (N + 255) / 256;
    const int prep_blocks = 416 + n_blocks;
    const int gb          = (N + 15) / 16;
    const int attn_blocks = (N + 3) / 4;            // 1 node/wave, 4 waves/blk

    // ---- prep: fused conversions + zero deg ----
    prep_misc<<<prep_blocks, 256, 0, stream>>>(
        Wq1, Wk1, Wv1, Ws1, bq1, bk1, bv1, bs1,
        Wq2, Wk2, Wv2, Ws2, bq2, bk2, bv2, bs2,
        wt1, ba1, wt2, ba2, deg, N);

    // ---- conv1 GEMM + degree histogram (fused, both only need prep) ----
    gemm1_hist<<<gb + e_blocks, 256, 0, stream>>>(
        x, wt1, ba1, qb, kb8, vb, skip, N, dstp, deg, E, gb);

    // ---- CSR scan + fill ----
    scanA<<<n_blocks, 256, 0, stream>>>(deg, bsum, N);
    scanB<<<1, 256, 0, stream>>>(bsum, bpre, n_blocks);
    scanC<<<n_blocks, 256, 0, stream>>>(deg, bpre, off, cursor, N, E);
    fill_kernel<<<e_blocks, 256, 0, stream>>>(src, dstp, cursor, csr, E);

    // ---- conv1 attention (writes h bf16) ----
    fused_attn<1, 1, 0><<<attn_blocks, 256, 0, stream>>>(
        qb, kb8, vb, skip, off, csr, lng, lnb, xbf, nullptr, nullptr, nullptr, N);

    // ---- conv2 GEMM ----
    gemm_qkvs2<<<gb, 256, 0, stream>>>(xbf, wt2, ba2, qb, kb8, vb, skip, N);

    // ---- conv2 attention + fused final LN/Linear -> d_out ----
    fused_attn<0, 0, 1><<<attn_blocks, 256, 0, stream>>>(
        qb, kb8, vb, skip, off, csr, lng, lnb, nullptr, Wf, bf, (float*)d_out, N);
}

// Round 13
// 368.166 us; speedup vs baseline: 1.1476x; 1.1018x over previous
//
#include <hip/hip_runtime.h>
#include <hip/hip_bf16.h>
#include <math.h>

typedef unsigned short u16;
typedef unsigned char u8;
typedef __attribute__((ext_vector_type(8))) short bf16x8;
typedef __attribute__((ext_vector_type(4))) float f32x4;
typedef __attribute__((ext_vector_type(2))) float f32x2;
typedef _Float16 f16;
typedef __attribute__((ext_vector_type(2))) _Float16 f16x2;

#if __has_builtin(__builtin_amdgcn_cvt_pk_f32_fp8) && __has_builtin(__builtin_amdgcn_cvt_pk_fp8_f32)
#define HAS_FP8 1
#else
#define HAS_FP8 0
#endif

__device__ __forceinline__ u16 f2bf(float f) {
    unsigned u = __float_as_uint(f);
    u += 0x7fffu + ((u >> 16) & 1u);   // RNE
    return (u16)(u >> 16);
}
__device__ __forceinline__ u16 f2h(float f) {
    return __builtin_bit_cast(u16, (f16)f);   // v_cvt_f16_f32 (RNE)
}
__device__ __forceinline__ f16x2 u2h(int u) {
    return __builtin_bit_cast(f16x2, u);
}

#if HAS_FP8
typedef uint2 kreg_t;     // 8 fp8 ch per lane
typedef uint2 vreg_t;     // 8 fp8 ch per lane
__device__ __forceinline__ float dotqk(kreg_t K, const float qf[8]) {
    f32x2 d0 = __builtin_amdgcn_cvt_pk_f32_fp8(K.x, false);
    f32x2 d1 = __builtin_amdgcn_cvt_pk_f32_fp8(K.x, true);
    f32x2 d2 = __builtin_amdgcn_cvt_pk_f32_fp8(K.y, false);
    f32x2 d3 = __builtin_amdgcn_cvt_pk_f32_fp8(K.y, true);
    float p = d0.x * qf[0];
    p = fmaf(d0.y, qf[1], p); p = fmaf(d1.x, qf[2], p); p = fmaf(d1.y, qf[3], p);
    p = fmaf(d2.x, qf[4], p); p = fmaf(d2.y, qf[5], p);
    p = fmaf(d3.x, qf[6], p); p = fmaf(d3.y, qf[7], p);
    return p;
}
__device__ __forceinline__ void dec8(vreg_t V, float w[8]) {
    f32x2 a0 = __builtin_amdgcn_cvt_pk_f32_fp8(V.x, false);
    f32x2 a1 = __builtin_amdgcn_cvt_pk_f32_fp8(V.x, true);
    f32x2 a2 = __builtin_amdgcn_cvt_pk_f32_fp8(V.y, false);
    f32x2 a3 = __builtin_amdgcn_cvt_pk_f32_fp8(V.y, true);
    w[0] = a0.x; w[1] = a0.y; w[2] = a1.x; w[3] = a1.y;
    w[4] = a2.x; w[5] = a2.y; w[6] = a3.x; w[7] = a3.y;
}
#else
typedef int4 kreg_t;
typedef int4 vreg_t;
__device__ __forceinline__ float dotqk(kreg_t K, const float qf[8]) {
    f16x2 t0 = u2h(K.x), t1 = u2h(K.y), t2 = u2h(K.z), t3 = u2h(K.w);
    float p = (float)t0.x * qf[0];
    p = fmaf((float)t0.y, qf[1], p); p = fmaf((float)t1.x, qf[2], p);
    p = fmaf((float)t1.y, qf[3], p); p = fmaf((float)t2.x, qf[4], p);
    p = fmaf((float)t2.y, qf[5], p); p = fmaf((float)t3.x, qf[6], p);
    p = fmaf((float)t3.y, qf[7], p);
    return p;
}
__device__ __forceinline__ void dec8(vreg_t V, float w[8]) {
    f16x2 t0 = u2h(V.x), t1 = u2h(V.y), t2 = u2h(V.z), t3 = u2h(V.w);
    w[0] = (float)t0.x; w[1] = (float)t0.y;
    w[2] = (float)t1.x; w[3] = (float)t1.y;
    w[4] = (float)t2.x; w[5] = (float)t2.y;
    w[6] = (float)t3.x; w[7] = (float)t3.y;
}
#endif

// ---------------------------------------------------------------------------
// prep_misc: grid-partitioned fusion of {convert W1, convert W2, zero deg}.
// wt[832][64] bf16 (cols 0-255 q *0.125 folded, 256-511 k, 512-767 v,
// 768-831 s), bias ba[832] fp32 (q part *0.125).
// ---------------------------------------------------------------------------
__device__ __forceinline__ void conv_w_one(
    int idx,
    const float* __restrict__ Wq, const float* __restrict__ Wk,
    const float* __restrict__ Wv, const float* __restrict__ Ws,
    const float* __restrict__ bq, const float* __restrict__ bk,
    const float* __restrict__ bv, const float* __restrict__ bs,
    u16* __restrict__ wt, float* __restrict__ ba)
{
    int col = idx >> 6, k = idx & 63;
    float w;
    if      (col < 256) w = Wq[k * 256 + col] * 0.125f;          // fold 1/sqrt(C)
    else if (col < 512) w = Wk[k * 256 + (col - 256)];
    else if (col < 768) w = Wv[k * 256 + (col - 512)];
    else                w = Ws[k * 64  + (col - 768)];
    wt[col * 64 + k] = f2bf(w);
    if (k == 0)
        ba[col] = (col < 256) ? bq[col] * 0.125f : (col < 512) ? bk[col - 256]
                 : (col < 768) ? bv[col - 512] : bs[col - 768];
}

__global__ __launch_bounds__(256) void prep_misc(
    const float* __restrict__ Wq1, const float* __restrict__ Wk1,
    const float* __restrict__ Wv1, const float* __restrict__ Ws1,
    const float* __restrict__ bq1, const float* __restrict__ bk1,
    const float* __restrict__ bv1, const float* __restrict__ bs1,
    const float* __restrict__ Wq2, const float* __restrict__ Wk2,
    const float* __restrict__ Wv2, const float* __restrict__ Ws2,
    const float* __restrict__ bq2, const float* __restrict__ bk2,
    const float* __restrict__ bv2, const float* __restrict__ bs2,
    u16* __restrict__ wt1, float* __restrict__ ba1,
    u16* __restrict__ wt2, float* __restrict__ ba2,
    int* __restrict__ deg, int n)
{
    int b = blockIdx.x, t = threadIdx.x;
    if (b < 208) {
        conv_w_one(b * 256 + t, Wq1, Wk1, Wv1, Ws1, bq1, bk1, bv1, bs1, wt1, ba1);
    } else if (b < 416) {
        conv_w_one((b - 208) * 256 + t, Wq2, Wk2, Wv2, Ws2, bq2, bk2, bv2, bs2, wt2, ba2);
    } else {
        int i = (b - 416) * 256 + t;
        if (i < n) deg[i] = 0;
    }
}

// ---------------------------------------------------------------------------
// CSR scan (3-phase coalesced) + fill
// ---------------------------------------------------------------------------
__global__ __launch_bounds__(256) void scanA(
    const int* __restrict__ deg, int* __restrict__ bsum, int n)
{
    int i = blockIdx.x * 256 + threadIdx.x;
    int v = (i < n) ? deg[i] : 0;
    #pragma unroll
    for (int o = 32; o; o >>= 1) v += __shfl_xor(v, o);
    __shared__ int wsum[4];
    if ((threadIdx.x & 63) == 0) wsum[threadIdx.x >> 6] = v;
    __syncthreads();
    if (threadIdx.x == 0)
        bsum[blockIdx.x] = wsum[0] + wsum[1] + wsum[2] + wsum[3];
}

__global__ __launch_bounds__(256) void scanB(
    const int* __restrict__ bsum, int* __restrict__ bpre, int nb)
{
    int t = threadIdx.x;
    int v = (t < nb) ? bsum[t] : 0;
    int lane = t & 63, wv = t >> 6;
    int sv = v;
    #pragma unroll
    for (int o = 1; o < 64; o <<= 1) {
        int u = __shfl_up(sv, o);
        if (lane >= o) sv += u;
    }
    __shared__ int wsum[4];
    if (lane == 63) wsum[wv] = sv;
    __syncthreads();
    int add = 0;
    for (int k = 0; k < wv; ++k) add += wsum[k];
    if (t < nb) bpre[t] = sv + add - v;   // exclusive
}

__global__ __launch_bounds__(256) void scanC(
    const int* __restrict__ deg, const int* __restrict__ bpre,
    int* __restrict__ off, int* __restrict__ cursor, int n, int E)
{
    int i = blockIdx.x * 256 + threadIdx.x;
    int v = (i < n) ? deg[i] : 0;
    int lane = threadIdx.x & 63, wv = threadIdx.x >> 6;
    int sv = v;
    #pragma unroll
    for (int o = 1; o < 64; o <<= 1) {
        int u = __shfl_up(sv, o);
        if (lane >= o) sv += u;
    }
    __shared__ int wsum[4];
    if (lane == 63) wsum[wv] = sv;
    __syncthreads();
    int add = bpre[blockIdx.x];
    for (int k = 0; k < wv; ++k) add += wsum[k];
    int excl = add + sv - v;
    if (i < n) {
        off[i] = excl; cursor[i] = excl;
        if (i == n - 1) off[n] = E;
    }
}

__global__ __launch_bounds__(256) void fill_kernel(
    const int* __restrict__ src, const int* __restrict__ dst,
    int* __restrict__ cursor, int* __restrict__ csr_src, int E)
{
    int e = blockIdx.x * 256 + threadIdx.x;
    if (e >= E) return;
    int slot = atomicAdd(&cursor[dst[e]], 1);
    csr_src[slot] = src[e];
}

// ---------------------------------------------------------------------------
// bf16 MFMA GEMM body (device fn). W as A-operand / X as B-operand; each
// lane owns 4 consecutive output cols of one node. q f16, k fp8, v fp8,
// skip f16. FP32IN: fp32 X in-register cvt.
// ---------------------------------------------------------------------------
template <int FP32IN>
__device__ __forceinline__ void gemm_body(
    int blk, const void* __restrict__ Xv, const u16* __restrict__ wt,
    const float* __restrict__ ba,
    u16* __restrict__ qb, u8* __restrict__ kb8, u8* __restrict__ vb8,
    u16* __restrict__ skip, int n)
{
    const int w = threadIdx.x >> 6, lane = threadIdx.x & 63;
    const int r = lane & 15, g = lane >> 4;
    const int node0 = blk * 16;

    int nr = node0 + r; if (nr >= n) nr = n - 1;
    bf16x8 b0, b1;                            // X fragment (B operand)
    if (FP32IN) {
        const float* xr = (const float*)Xv + (size_t)nr * 64 + g * 8;
        float t0[8], t1[8];
        *(float4*)(t0)     = ((const float4*)xr)[0];
        *(float4*)(t0 + 4) = ((const float4*)xr)[1];
        *(float4*)(t1)     = ((const float4*)(xr + 32))[0];
        *(float4*)(t1 + 4) = ((const float4*)(xr + 32))[1];
        #pragma unroll
        for (int j = 0; j < 8; ++j) {
            b0[j] = (short)f2bf(t0[j]);
            b1[j] = (short)f2bf(t1[j]);
        }
    } else {
        const u16* xr = (const u16*)Xv + (size_t)nr * 64 + g * 8;
        b0 = *(const bf16x8*)xr;
        b1 = *(const bf16x8*)(xr + 32);
    }

    const int colbase = w * 208;
    const int node = node0 + r;

    const u16* wr0 = wt + (size_t)(colbase + r) * 64 + g * 8;
    bf16x8 a0 = *(const bf16x8*)wr0;
    bf16x8 a1 = *(const bf16x8*)(wr0 + 32);

    for (int ct = 0; ct < 13; ++ct) {
        int ctn = (ct + 1 < 13) ? ct + 1 : 12;
        const u16* wrn = wt + (size_t)(colbase + ctn * 16 + r) * 64 + g * 8;
        bf16x8 an0 = *(const bf16x8*)wrn;
        bf16x8 an1 = *(const bf16x8*)(wrn + 32);

        f32x4 acc = {0.f, 0.f, 0.f, 0.f};
        acc = __builtin_amdgcn_mfma_f32_16x16x32_bf16(a0, b0, acc, 0, 0, 0);
        acc = __builtin_amdgcn_mfma_f32_16x16x32_bf16(a1, b1, acc, 0, 0, 0);
        int col0 = colbase + ct * 16 + g * 4;
        float4 bias = *(const float4*)(ba + col0);
        if (node < n) {
            float v0 = acc[0] + bias.x, v1 = acc[1] + bias.y;
            float v2 = acc[2] + bias.z, v3 = acc[3] + bias.w;
            if (col0 < 256) {
                ushort4 o;
                o.x = f2h(v0); o.y = f2h(v1); o.z = f2h(v2); o.w = f2h(v3);
                *(ushort4*)(qb + (size_t)node * 256 + col0) = o;
            } else if (col0 < 512) {
                int c = col0 - 256;
#if HAS_FP8
                unsigned pk = __builtin_amdgcn_cvt_pk_fp8_f32(v0, v1, 0u, false);
                pk = __builtin_amdgcn_cvt_pk_fp8_f32(v2, v3, pk, true);
                *(unsigned*)(kb8 + (size_t)node * 256 + c) = pk;
#else
                ushort4 o;
                o.x = f2h(v0); o.y = f2h(v1); o.z = f2h(v2); o.w = f2h(v3);
                *(ushort4*)((u16*)kb8 + (size_t)node * 256 + c) = o;
#endif
            } else if (col0 < 768) {
                int c = col0 - 512;
#if HAS_FP8
                unsigned pk = __builtin_amdgcn_cvt_pk_fp8_f32(v0, v1, 0u, false);
                pk = __builtin_amdgcn_cvt_pk_fp8_f32(v2, v3, pk, true);
                *(unsigned*)(vb8 + (size_t)node * 256 + c) = pk;
#else
                ushort4 o;
                o.x = f2h(v0); o.y = f2h(v1); o.z = f2h(v2); o.w = f2h(v3);
                *(ushort4*)((u16*)vb8 + (size_t)node * 256 + c) = o;
#endif
            } else {
                ushort4 o;
                o.x = f2h(v0); o.y = f2h(v1); o.z = f2h(v2); o.w = f2h(v3);
                *(ushort4*)(skip + (size_t)node * 64 + (col0 - 768)) = o;
            }
        }
        a0 = an0; a1 = an1;
    }
}

// gemm1 fused with degree histogram (both depend only on prep_misc)
__global__ __launch_bounds__(256) void gemm1_hist(
    const float* __restrict__ x, const u16* __restrict__ wt,
    const float* __restrict__ ba,
    u16* __restrict__ qb, u8* __restrict__ kb8, u8* __restrict__ vb8,
    u16* __restrict__ skip, int n,
    const int* __restrict__ dst, int* __restrict__ deg, int E, int gb)
{
    int b = blockIdx.x;
    if (b < gb) {
        gemm_body<1>(b, x, wt, ba, qb, kb8, vb8, skip, n);
    } else {
        int e = (b - gb) * 256 + threadIdx.x;
        if (e < E) atomicAdd(&deg[dst[e]], 1);
    }
}

__global__ __launch_bounds__(256) void gemm_qkvs2(
    const u16* __restrict__ xbf, const u16* __restrict__ wt,
    const float* __restrict__ ba,
    u16* __restrict__ qb, u8* __restrict__ kb8, u8* __restrict__ vb8,
    u16* __restrict__ skip, int n)
{
    gemm_body<0>(blockIdx.x, xbf, wt, ba, qb, kb8, vb8, skip, n);
}

// ---------------------------------------------------------------------------
// Fused attention: ONE node per wave, TWO edge-streams (half-wave each,
// edges t = 2i+half). fp8 k AND v (8B/lane each), defer-max (THR=8),
// clamped 3-deep prefetch ring under #pragma unroll 3.
// FINAL: fuse LayerNorm output through LDS into the 64->32 matvec (d_out).
// ---------------------------------------------------------------------------
template <int RELU, int BF16OUT, int FINAL>
__global__ __launch_bounds__(256) void fused_attn(
    const u16* __restrict__ qb, const u8* __restrict__ kb8,
    const u8* __restrict__ vb8, const u16* __restrict__ skip,
    const int* __restrict__ off, const int* __restrict__ csr,
    const float* __restrict__ lng, const float* __restrict__ lnb,
    u16* __restrict__ out_bf,
    const float* __restrict__ Wf, const float* __restrict__ bfv,
    float* __restrict__ outF, int n)
{
    const int lane = threadIdx.x & 63;
    const int half = lane >> 5;          // edge-stream parity
    const int hl   = lane & 31;          // h*8 + c8
    const int c8   = lane & 7;
    const int wv   = threadIdx.x >> 6;
    const int node = blockIdx.x * 4 + wv;
    const bool nvalid = node < n;
    const int nodeC = nvalid ? node : n - 1;

    // q: decode f16 row slice to f32 (1/sqrt(C) pre-folded into Wq)
    const int4 qw = *(const int4*)(qb + (size_t)nodeC * 256 + hl * 8);
    float qf[8];
    {
        f16x2 t0 = u2h(qw.x), t1 = u2h(qw.y), t2 = u2h(qw.z), t3 = u2h(qw.w);
        qf[0] = (float)t0.x; qf[1] = (float)t0.y;
        qf[2] = (float)t1.x; qf[3] = (float)t1.y;
        qf[4] = (float)t2.x; qf[5] = (float)t2.y;
        qf[6] = (float)t3.x; qf[7] = (float)t3.y;
    }

    const int s0 = off[nodeC], s1 = off[nodeC + 1];
    const int deg = nvalid ? (s1 - s0) : 0;
    const int imax = (deg + 1) >> 1;     // iterations per stream

    float m = -1e30f, l = 0.f;
    float a[8] = {0.f, 0.f, 0.f, 0.f, 0.f, 0.f, 0.f, 0.f};

    if (imax > 0) {
#if HAS_FP8
        const u8* kbase = kb8 + hl * 8;
        const u8* vbase = vb8 + hl * 8;
#else
        const u16* kbase = (const u16*)kb8 + hl * 8;
        const u16* vbase = (const u16*)vb8 + hl * 8;
#endif
        // clamped: tail loads re-read row csr[s1-1] (cache-hot, masked out)
        #define LOADKV(I, K, V) { \
            int _ix = min(s0 + 2 * (I) + half, s1 - 1); \
            int _s = csr[_ix]; \
            K = *(const kreg_t*)(kbase + (size_t)_s * 256); \
            V = *(const vreg_t*)(vbase + (size_t)_s * 256); }

        kreg_t k0, k1, k2;
        vreg_t v0, v1, v2;
        LOADKV(0, k0, v0);
        LOADKV(1, k1, v1);
        LOADKV(2, k2, v2);

        #pragma unroll 3
        for (int i = 0; i < imax; ++i) {
            kreg_t kn; vreg_t vn;
            LOADKV(i + 3, kn, vn);

            float p = dotqk(k0, qf);
            p += __shfl_xor(p, 1);
            p += __shfl_xor(p, 2);
            p += __shfl_xor(p, 4);
            p = (2 * i + half < deg) ? p : -2e30f;   // tail mask

            float w[8];
            dec8(v0, w);
            if (__all(p - m <= 8.f)) {
                // defer-max fast path: no rescale (P bounded by e^8)
                float e = __expf(p - m);
                l += e;
                #pragma unroll
                for (int j = 0; j < 8; ++j) a[j] = fmaf(e, w[j], a[j]);
            } else {
                float nm = fmaxf(m, p);
                float c = __expf(m - nm);
                float e = __expf(p - nm);
                m = nm;
                l = l * c + e;
                #pragma unroll
                for (int j = 0; j < 8; ++j) a[j] = fmaf(e, w[j], a[j] * c);
            }

            k0 = k1; v0 = v1; k1 = k2; v1 = v2; k2 = kn; v2 = vn;
        }
        #undef LOADKV
    }

    // merge the two streams (lane ^ 32 holds the partner state)
    {
        float mo = __shfl_xor(m, 32);
        float lo_ = __shfl_xor(l, 32);
        float nm = fmaxf(m, mo);
        float c  = __expf(m - nm);
        float co = __expf(mo - nm);
        l = l * c + lo_ * co;
        #pragma unroll
        for (int j = 0; j < 8; ++j) {
            float ao = __shfl_xor(a[j], 32);
            a[j] = a[j] * c + ao * co;
        }
    }

    // normalize per head, then mean over heads (hl bits 3,4)
    const float inv = 0.25f / (l + 1e-16f);
    #pragma unroll
    for (int j = 0; j < 8; ++j) {
        a[j] *= inv;
        a[j] += __shfl_xor(a[j], 8);
        a[j] += __shfl_xor(a[j], 16);
    }

    // skip connection (f16): channels c8*8 .. +7
    const int4 skw = *(const int4*)(skip + (size_t)nodeC * 64 + c8 * 8);
    f16x2 s0_ = u2h(skw.x), s1_ = u2h(skw.y), s2_ = u2h(skw.z), s3_ = u2h(skw.w);
    float o[8];
    o[0] = a[0] + (float)s0_.x; o[1] = a[1] + (float)s0_.y;
    o[2] = a[2] + (float)s1_.x; o[3] = a[3] + (float)s1_.y;
    o[4] = a[4] + (float)s2_.x; o[5] = a[5] + (float)s2_.y;
    o[6] = a[6] + (float)s3_.x; o[7] = a[7] + (float)s3_.y;

    // LayerNorm over 64 channels (8 lanes x 8 ch within each 8-lane group)
    float s = o[0] + o[1] + o[2] + o[3] + o[4] + o[5] + o[6] + o[7];
    s += __shfl_xor(s, 1); s += __shfl_xor(s, 2); s += __shfl_xor(s, 4);
    const float mu = s * (1.f / 64.f);
    float vs = 0.f;
    #pragma unroll
    for (int j = 0; j < 8; ++j) { o[j] -= mu; vs = fmaf(o[j], o[j], vs); }
    vs += __shfl_xor(vs, 1); vs += __shfl_xor(vs, 2); vs += __shfl_xor(vs, 4);
    const float rs = rsqrtf(vs * (1.f / 64.f) + 1e-5f);

    const float4* gp = (const float4*)(lng + c8 * 8);
    const float4* bp = (const float4*)(lnb + c8 * 8);
    float4 g0 = gp[0], g1 = gp[1], b0 = bp[0], b1 = bp[1];
    float y[8];
    y[0] = o[0] * rs * g0.x + b0.x; y[1] = o[1] * rs * g0.y + b0.y;
    y[2] = o[2] * rs * g0.z + b0.z; y[3] = o[3] * rs * g0.w + b0.w;
    y[4] = o[4] * rs * g1.x + b1.x; y[5] = o[5] * rs * g1.y + b1.y;
    y[6] = o[6] * rs * g1.z + b1.z; y[7] = o[7] * rs * g1.w + b1.w;
    if (RELU) {
        #pragma unroll
        for (int j = 0; j < 8; ++j) y[j] = fmaxf(y[j], 0.f);
    }

    if (FINAL) {
        // fused 64->32 matvec via LDS (y of 4 nodes staged per block)
        __shared__ float yl[4][64];
        if (lane < 8) {
            #pragma unroll
            for (int j = 0; j < 8; ++j) yl[wv][c8 * 8 + j] = y[j];
        }
        __syncthreads();
        int t = threadIdx.x;
        if (t < 128) {
            int nd = t >> 5, oc = t & 31;
            int gn = blockIdx.x * 4 + nd;
            if (gn < n) {
                float acc = bfv[oc];
                #pragma unroll
                for (int c = 0; c < 64; ++c)
                    acc = fmaf(yl[nd][c], Wf[c * 32 + oc], acc);
                outF[(size_t)gn * 32 + oc] = acc;
            }
        }
    } else if (lane < 8 && nvalid) {
        if (BF16OUT) {
            bf16x8 ob;
            #pragma unroll
            for (int j = 0; j < 8; ++j) ob[j] = (short)f2bf(y[j]);
            *(bf16x8*)(out_bf + (size_t)node * 64 + c8 * 8) = ob;
        }
    }
}

// ---------------------------------------------------------------------------
extern "C" void kernel_launch(void* const* d_in, const int* in_sizes, int n_in,
                              void* d_out, int out_size, void* d_ws, size_t ws_size,
                              hipStream_t stream)
{
    const float* x   = (const float*)d_in[0];
    const int*   ei  = (const int*)d_in[1];
    const float* Wq1 = (const float*)d_in[2];  const float* bq1 = (const float*)d_in[3];
    const float* Wk1 = (const float*)d_in[4];  const float* bk1 = (const float*)d_in[5];
    const float* Wv1 = (const float*)d_in[6];  const float* bv1 = (const float*)d_in[7];
    const float* Ws1 = (const float*)d_in[8];  const float* bs1 = (const float*)d_in[9];
    const float* Wq2 = (const float*)d_in[10]; const float* bq2 = (const float*)d_in[11];
    const float* Wk2 = (const float*)d_in[12]; const float* bk2 = (const float*)d_in[13];
    const float* Wv2 = (const float*)d_in[14]; const float* bv2 = (const float*)d_in[15];
    const float* Ws2 = (const float*)d_in[16]; const float* bs2 = (const float*)d_in[17];
    const float* lng = (const float*)d_in[18]; const float* lnb = (const float*)d_in[19];
    const float* Wf  = (const float*)d_in[20]; const float* bf  = (const float*)d_in[21];

    const int N = in_sizes[0] / 64;
    const int E = in_sizes[1] / 2;
    const int* src  = ei;
    const int* dstp = ei + E;

    char* p = (char*)d_ws;
    u16* qb   = (u16*)p; p += (size_t)N * 256 * 2;   // f16
    u8*  kb8  = (u8*)p;  p += (size_t)N * 256 * 2;   // fp8 (f16 fallback fits)
    u8*  vb8  = (u8*)p;  p += (size_t)N * 256 * 2;   // fp8 (f16 fallback fits)
    u16* xbf  = (u16*)p; p += (size_t)N * 64 * 2;    // conv1 output h (bf16)
    u16* wt1  = (u16*)p; p += 832 * 64 * 2;
    u16* wt2  = (u16*)p; p += 832 * 64 * 2;
    float* ba1  = (float*)p; p += 832 * 4;
    float* ba2  = (float*)p; p += 832 * 4;
    u16* skip = (u16*)p; p += (size_t)N * 64 * 2;    // f16
    int* deg    = (int*)p; p += (size_t)N * 4;
    int* off    = (int*)p; p += ((size_t)N + 1) * 4;
    int* cursor = (int*)p; p += (size_t)N * 4;
    int* csr    = (int*)p; p += (size_t)E * 4;
    int* bsum   = (int*)p; p += 1024;
    int* bpre   = (int*)p; p += 1024;

    const int e_blocks    = (E + 255) / 256;
    const int n_blocks    = (N + 255) / 256;
    const int prep_blocks = 416 + n_blocks;
    const int gb          = (N + 15) / 16;
    const int attn_blocks = (N + 3) / 4;            // 1 node/wave, 4 waves/blk

    // ---- prep: fused conversions + zero deg ----
    prep_misc<<<prep_blocks, 256, 0, stream>>>(
        Wq1, Wk1, Wv1, Ws1, bq1, bk1, bv1, bs1,
        Wq2, Wk2, Wv2, Ws2, bq2, bk2, bv2, bs2,
        wt1, ba1, wt2, ba2, deg, N);

    // ---- conv1 GEMM + degree histogram (fused, both only need prep) ----
    gemm1_hist<<<gb + e_blocks, 256, 0, stream>>>(
        x, wt1, ba1, qb, kb8, vb8, skip, N, dstp, deg, E, gb);

    // ---- CSR scan + fill ----
    scanA<<<n_blocks, 256, 0, stream>>>(deg, bsum, N);
    scanB<<<1, 256, 0, stream>>>(bsum, bpre, n_blocks);
    scanC<<<n_blocks, 256, 0, stream>>>(deg, bpre, off, cursor, N, E);
    fill_kernel<<<e_blocks, 256, 0, stream>>>(src, dstp, cursor, csr, E);

    // ---- conv1 attention (writes h bf16) ----
    fused_attn<1, 1, 0><<<attn_blocks, 256, 0, stream>>>(
        qb, kb8, vb8, skip, off, csr, lng, lnb, xbf, nullptr, nullptr, nullptr, N);

    // ---- conv2 GEMM ----
    gemm_qkvs2<<<gb, 256, 0, stream>>>(xbf, wt2, ba2, qb, kb8, vb8, skip, N);

    // ---- conv2 attention + fused final LN/Linear -> d_out ----
    fused_attn<0, 0, 1><<<attn_blocks, 256, 0, stream>>>(
        qb, kb8, vb8, skip, off, csr, lng, lnb, nullptr, Wf, bf, (float*)d_out, N);
}

// Round 15
// 335.283 us; speedup vs baseline: 1.2602x; 1.0981x over previous
//
#include <hip/hip_runtime.h>
#include <hip/hip_bf16.h>
#include <math.h>

typedef unsigned short u16;
typedef unsigned char u8;
typedef __attribute__((ext_vector_type(8))) short bf16x8;
typedef __attribute__((ext_vector_type(4))) float f32x4;
typedef __attribute__((ext_vector_type(2))) float f32x2;
typedef _Float16 f16;
typedef __attribute__((ext_vector_type(2))) _Float16 f16x2;

#if __has_builtin(__builtin_amdgcn_cvt_pk_f32_fp8) && __has_builtin(__builtin_amdgcn_cvt_pk_fp8_f32)
#define HAS_FP8 1
#else
#define HAS_FP8 0
#endif

__device__ __forceinline__ u16 f2bf(float f) {
    unsigned u = __float_as_uint(f);
    u += 0x7fffu + ((u >> 16) & 1u);   // RNE
    return (u16)(u >> 16);
}
__device__ __forceinline__ u16 f2h(float f) {
    return __builtin_bit_cast(u16, (f16)f);   // v_cvt_f16_f32 (RNE)
}
__device__ __forceinline__ f16x2 u2h(int u) {
    return __builtin_bit_cast(f16x2, u);
}

#if HAS_FP8
__device__ __forceinline__ float dotqk2(unsigned lo, unsigned hi, const float qf[8]) {
    f32x2 d0 = __builtin_amdgcn_cvt_pk_f32_fp8(lo, false);
    f32x2 d1 = __builtin_amdgcn_cvt_pk_f32_fp8(lo, true);
    f32x2 d2 = __builtin_amdgcn_cvt_pk_f32_fp8(hi, false);
    f32x2 d3 = __builtin_amdgcn_cvt_pk_f32_fp8(hi, true);
    float p = d0.x * qf[0];
    p = fmaf(d0.y, qf[1], p); p = fmaf(d1.x, qf[2], p); p = fmaf(d1.y, qf[3], p);
    p = fmaf(d2.x, qf[4], p); p = fmaf(d2.y, qf[5], p);
    p = fmaf(d3.x, qf[6], p); p = fmaf(d3.y, qf[7], p);
    return p;
}
__device__ __forceinline__ void dec8v(unsigned lo, unsigned hi, float w[8]) {
    f32x2 a0 = __builtin_amdgcn_cvt_pk_f32_fp8(lo, false);
    f32x2 a1 = __builtin_amdgcn_cvt_pk_f32_fp8(lo, true);
    f32x2 a2 = __builtin_amdgcn_cvt_pk_f32_fp8(hi, false);
    f32x2 a3 = __builtin_amdgcn_cvt_pk_f32_fp8(hi, true);
    w[0] = a0.x; w[1] = a0.y; w[2] = a1.x; w[3] = a1.y;
    w[4] = a2.x; w[5] = a2.y; w[6] = a3.x; w[7] = a3.y;
}
#else
__device__ __forceinline__ float dotqk_h(int4 K, const float qf[8]) {
    f16x2 t0 = u2h(K.x), t1 = u2h(K.y), t2 = u2h(K.z), t3 = u2h(K.w);
    float p = (float)t0.x * qf[0];
    p = fmaf((float)t0.y, qf[1], p); p = fmaf((float)t1.x, qf[2], p);
    p = fmaf((float)t1.y, qf[3], p); p = fmaf((float)t2.x, qf[4], p);
    p = fmaf((float)t2.y, qf[5], p); p = fmaf((float)t3.x, qf[6], p);
    p = fmaf((float)t3.y, qf[7], p);
    return p;
}
__device__ __forceinline__ void dec8_h(int4 V, float w[8]) {
    f16x2 t0 = u2h(V.x), t1 = u2h(V.y), t2 = u2h(V.z), t3 = u2h(V.w);
    w[0] = (float)t0.x; w[1] = (float)t0.y;
    w[2] = (float)t1.x; w[3] = (float)t1.y;
    w[4] = (float)t2.x; w[5] = (float)t2.y;
    w[6] = (float)t3.x; w[7] = (float)t3.y;
}
#endif

// ---------------------------------------------------------------------------
// prep_misc: grid-partitioned fusion of {convert W1, convert W2, zero deg}.
// wt[832][64] bf16 (cols 0-255 q *0.125 folded, 256-511 k, 512-767 v,
// 768-831 s), bias ba[832] fp32 (q part *0.125).
// ---------------------------------------------------------------------------
__device__ __forceinline__ void conv_w_one(
    int idx,
    const float* __restrict__ Wq, const float* __restrict__ Wk,
    const float* __restrict__ Wv, const float* __restrict__ Ws,
    const float* __restrict__ bq, const float* __restrict__ bk,
    const float* __restrict__ bv, const float* __restrict__ bs,
    u16* __restrict__ wt, float* __restrict__ ba)
{
    int col = idx >> 6, k = idx & 63;
    float w;
    if      (col < 256) w = Wq[k * 256 + col] * 0.125f;          // fold 1/sqrt(C)
    else if (col < 512) w = Wk[k * 256 + (col - 256)];
    else if (col < 768) w = Wv[k * 256 + (col - 512)];
    else                w = Ws[k * 64  + (col - 768)];
    wt[col * 64 + k] = f2bf(w);
    if (k == 0)
        ba[col] = (col < 256) ? bq[col] * 0.125f : (col < 512) ? bk[col - 256]
                 : (col < 768) ? bv[col - 512] : bs[col - 768];
}

__global__ __launch_bounds__(256) void prep_misc(
    const float* __restrict__ Wq1, const float* __restrict__ Wk1,
    const float* __restrict__ Wv1, const float* __restrict__ Ws1,
    const float* __restrict__ bq1, const float* __restrict__ bk1,
    const float* __restrict__ bv1, const float* __restrict__ bs1,
    const float* __restrict__ Wq2, const float* __restrict__ Wk2,
    const float* __restrict__ Wv2, const float* __restrict__ Ws2,
    const float* __restrict__ bq2, const float* __restrict__ bk2,
    const float* __restrict__ bv2, const float* __restrict__ bs2,
    u16* __restrict__ wt1, float* __restrict__ ba1,
    u16* __restrict__ wt2, float* __restrict__ ba2,
    int* __restrict__ deg, int n)
{
    int b = blockIdx.x, t = threadIdx.x;
    if (b < 208) {
        conv_w_one(b * 256 + t, Wq1, Wk1, Wv1, Ws1, bq1, bk1, bv1, bs1, wt1, ba1);
    } else if (b < 416) {
        conv_w_one((b - 208) * 256 + t, Wq2, Wk2, Wv2, Ws2, bq2, bk2, bv2, bs2, wt2, ba2);
    } else {
        int i = (b - 416) * 256 + t;
        if (i < n) deg[i] = 0;
    }
}

// ---------------------------------------------------------------------------
// CSR scan (3-phase coalesced) + fill
// ---------------------------------------------------------------------------
__global__ __launch_bounds__(256) void scanA(
    const int* __restrict__ deg, int* __restrict__ bsum, int n)
{
    int i = blockIdx.x * 256 + threadIdx.x;
    int v = (i < n) ? deg[i] : 0;
    #pragma unroll
    for (int o = 32; o; o >>= 1) v += __shfl_xor(v, o);
    __shared__ int wsum[4];
    if ((threadIdx.x & 63) == 0) wsum[threadIdx.x >> 6] = v;
    __syncthreads();
    if (threadIdx.x == 0)
        bsum[blockIdx.x] = wsum[0] + wsum[1] + wsum[2] + wsum[3];
}

__global__ __launch_bounds__(256) void scanB(
    const int* __restrict__ bsum, int* __restrict__ bpre, int nb)
{
    int t = threadIdx.x;
    int v = (t < nb) ? bsum[t] : 0;
    int lane = t & 63, wv = t >> 6;
    int sv = v;
    #pragma unroll
    for (int o = 1; o < 64; o <<= 1) {
        int u = __shfl_up(sv, o);
        if (lane >= o) sv += u;
    }
    __shared__ int wsum[4];
    if (lane == 63) wsum[wv] = sv;
    __syncthreads();
    int add = 0;
    for (int k = 0; k < wv; ++k) add += wsum[k];
    if (t < nb) bpre[t] = sv + add - v;   // exclusive
}

__global__ __launch_bounds__(256) void scanC(
    const int* __restrict__ deg, const int* __restrict__ bpre,
    int* __restrict__ off, int* __restrict__ cursor, int n, int E)
{
    int i = blockIdx.x * 256 + threadIdx.x;
    int v = (i < n) ? deg[i] : 0;
    int lane = threadIdx.x & 63, wv = threadIdx.x >> 6;
    int sv = v;
    #pragma unroll
    for (int o = 1; o < 64; o <<= 1) {
        int u = __shfl_up(sv, o);
        if (lane >= o) sv += u;
    }
    __shared__ int wsum[4];
    if (lane == 63) wsum[wv] = sv;
    __syncthreads();
    int add = bpre[blockIdx.x];
    for (int k = 0; k < wv; ++k) add += wsum[k];
    int excl = add + sv - v;
    if (i < n) {
        off[i] = excl; cursor[i] = excl;
        if (i == n - 1) off[n] = E;
    }
}

__global__ __launch_bounds__(256) void fill_kernel(
    const int* __restrict__ src, const int* __restrict__ dst,
    int* __restrict__ cursor, int* __restrict__ csr_src, int E)
{
    int e = blockIdx.x * 256 + threadIdx.x;
    if (e >= E) return;
    int slot = atomicAdd(&cursor[dst[e]], 1);
    csr_src[slot] = src[e];
}

// ---------------------------------------------------------------------------
// bf16 MFMA GEMM body: 32 nodes/block (two B-fragment groups share the same
// A/wt fragments -> half the wt traffic + A-prefetch per node). Each lane
// owns 4 consecutive output cols. q f16; k,v fp8 INTERLEAVED in kvb
// (per node: 32 lane-groups x {8B k, 8B v}); skip f16.
// ---------------------------------------------------------------------------
template <int FP32IN>
__device__ __forceinline__ void gemm_body(
    int blk, const void* __restrict__ Xv, const u16* __restrict__ wt,
    const float* __restrict__ ba,
    u16* __restrict__ qb, u8* __restrict__ kvb, u16* __restrict__ skip, int n)
{
    const int w = threadIdx.x >> 6, lane = threadIdx.x & 63;
    const int r = lane & 15, g = lane >> 4;
    const int node0 = blk * 32;

    bf16x8 bx0[2], bx1[2];                    // X fragments, 2 node groups
    #pragma unroll
    for (int grp = 0; grp < 2; ++grp) {
        int nr = node0 + grp * 16 + r; if (nr >= n) nr = n - 1;
        if (FP32IN) {
            const float* xr = (const float*)Xv + (size_t)nr * 64 + g * 8;
            float t0[8], t1[8];
            *(float4*)(t0)     = ((const float4*)xr)[0];
            *(float4*)(t0 + 4) = ((const float4*)xr)[1];
            *(float4*)(t1)     = ((const float4*)(xr + 32))[0];
            *(float4*)(t1 + 4) = ((const float4*)(xr + 32))[1];
            #pragma unroll
            for (int j = 0; j < 8; ++j) {
                bx0[grp][j] = (short)f2bf(t0[j]);
                bx1[grp][j] = (short)f2bf(t1[j]);
            }
        } else {
            const u16* xr = (const u16*)Xv + (size_t)nr * 64 + g * 8;
            bx0[grp] = *(const bf16x8*)xr;
            bx1[grp] = *(const bf16x8*)(xr + 32);
        }
    }

    const int colbase = w * 208;

    const u16* wr0 = wt + (size_t)(colbase + r) * 64 + g * 8;
    bf16x8 a0 = *(const bf16x8*)wr0;
    bf16x8 a1 = *(const bf16x8*)(wr0 + 32);

    for (int ct = 0; ct < 13; ++ct) {
        int ctn = (ct + 1 < 13) ? ct + 1 : 12;
        const u16* wrn = wt + (size_t)(colbase + ctn * 16 + r) * 64 + g * 8;
        bf16x8 an0 = *(const bf16x8*)wrn;
        bf16x8 an1 = *(const bf16x8*)(wrn + 32);

        int col0 = colbase + ct * 16 + g * 4;
        float4 bias = *(const float4*)(ba + col0);

        #pragma unroll
        for (int grp = 0; grp < 2; ++grp) {
            f32x4 acc = {0.f, 0.f, 0.f, 0.f};
            acc = __builtin_amdgcn_mfma_f32_16x16x32_bf16(a0, bx0[grp], acc, 0, 0, 0);
            acc = __builtin_amdgcn_mfma_f32_16x16x32_bf16(a1, bx1[grp], acc, 0, 0, 0);
            int node = node0 + grp * 16 + r;
            if (node < n) {
                float v0 = acc[0] + bias.x, v1 = acc[1] + bias.y;
                float v2 = acc[2] + bias.z, v3 = acc[3] + bias.w;
                if (col0 < 256) {
                    ushort4 o;
                    o.x = f2h(v0); o.y = f2h(v1); o.z = f2h(v2); o.w = f2h(v3);
                    *(ushort4*)(qb + (size_t)node * 256 + col0) = o;
                } else if (col0 < 768) {
                    const bool isK = col0 < 512;
                    int c = col0 - (isK ? 256 : 512);
#if HAS_FP8
                    unsigned pk = __builtin_amdgcn_cvt_pk_fp8_f32(v0, v1, 0u, false);
                    pk = __builtin_amdgcn_cvt_pk_fp8_f32(v2, v3, pk, true);
                    *(unsigned*)(kvb + (size_t)node * 512 + ((c >> 3) << 4)
                                 + (c & 7) + (isK ? 0 : 8)) = pk;
#else
                    ushort4 o;
                    o.x = f2h(v0); o.y = f2h(v1); o.z = f2h(v2); o.w = f2h(v3);
                    *(ushort4*)(kvb + (size_t)node * 1024 + ((c >> 3) << 5)
                                + ((c & 7) << 1) + (isK ? 0 : 16)) = o;
#endif
                } else {
                    ushort4 o;
                    o.x = f2h(v0); o.y = f2h(v1); o.z = f2h(v2); o.w = f2h(v3);
                    *(ushort4*)(skip + (size_t)node * 64 + (col0 - 768)) = o;
                }
            }
        }
        a0 = an0; a1 = an1;
    }
}

// gemm1 fused with degree histogram (both depend only on prep_misc)
__global__ __launch_bounds__(256) void gemm1_hist(
    const float* __restrict__ x, const u16* __restrict__ wt,
    const float* __restrict__ ba,
    u16* __restrict__ qb, u8* __restrict__ kvb, u16* __restrict__ skip, int n,
    const int* __restrict__ dst, int* __restrict__ deg, int E, int gb)
{
    int b = blockIdx.x;
    if (b < gb) {
        gemm_body<1>(b, x, wt, ba, qb, kvb, skip, n);
    } else {
        int e = (b - gb) * 256 + threadIdx.x;
        if (e < E) atomicAdd(&deg[dst[e]], 1);
    }
}

__global__ __launch_bounds__(256) void gemm_qkvs2(
    const u16* __restrict__ xbf, const u16* __restrict__ wt,
    const float* __restrict__ ba,
    u16* __restrict__ qb, u8* __restrict__ kvb, u16* __restrict__ skip, int n)
{
    gemm_body<0>(blockIdx.x, xbf, wt, ba, qb, kvb, skip, n);
}

// ---------------------------------------------------------------------------
// Fused attention: ONE node per wave, TWO edge-streams (half-wave each,
// edges t = 2i+half). Interleaved fp8 kv: ONE dwordx4 gather per lane per
// iteration (k = .x/.y, v = .z/.w). defer-max (THR=8), clamped 3-deep
// prefetch ring under #pragma unroll 3.
// FINAL: fuse LayerNorm output through LDS into the 64->32 matvec (d_out).
// ---------------------------------------------------------------------------
template <int RELU, int BF16OUT, int FINAL>
__global__ __launch_bounds__(256) void fused_attn(
    const u16* __restrict__ qb, const u8* __restrict__ kvb,
    const u16* __restrict__ skip,
    const int* __restrict__ off, const int* __restrict__ csr,
    const float* __restrict__ lng, const float* __restrict__ lnb,
    u16* __restrict__ out_bf,
    const float* __restrict__ Wf, const float* __restrict__ bfv,
    float* __restrict__ outF, int n)
{
    const int lane = threadIdx.x & 63;
    const int half = lane >> 5;          // edge-stream parity
    const int hl   = lane & 31;          // h*8 + c8
    const int c8   = lane & 7;
    const int wv   = threadIdx.x >> 6;
    const int node = blockIdx.x * 4 + wv;
    const bool nvalid = node < n;
    const int nodeC = nvalid ? node : n - 1;

    // q: decode f16 row slice to f32 (1/sqrt(C) pre-folded into Wq)
    const int4 qw = *(const int4*)(qb + (size_t)nodeC * 256 + hl * 8);
    float qf[8];
    {
        f16x2 t0 = u2h(qw.x), t1 = u2h(qw.y), t2 = u2h(qw.z), t3 = u2h(qw.w);
        qf[0] = (float)t0.x; qf[1] = (float)t0.y;
        qf[2] = (float)t1.x; qf[3] = (float)t1.y;
        qf[4] = (float)t2.x; qf[5] = (float)t2.y;
        qf[6] = (float)t3.x; qf[7] = (float)t3.y;
    }

    const int s0 = off[nodeC], s1 = off[nodeC + 1];
    const int deg = nvalid ? (s1 - s0) : 0;
    const int imax = (deg + 1) >> 1;     // iterations per stream

    float m = -1e30f, l = 0.f;
    float a[8] = {0.f, 0.f, 0.f, 0.f, 0.f, 0.f, 0.f, 0.f};

    if (imax > 0) {
#if HAS_FP8
        const u8* kvbase = kvb + hl * 16;
        // clamped: tail loads re-read row csr[s1-1] (cache-hot, masked out)
        #define LOADKV(I, KV) { \
            int _ix = min(s0 + 2 * (I) + half, s1 - 1); \
            int _s = csr[_ix]; \
            KV = *(const uint4*)(kvbase + (size_t)_s * 512); }

        uint4 kv0, kv1, kv2;
        LOADKV(0, kv0);
        LOADKV(1, kv1);
        LOADKV(2, kv2);

        #pragma unroll 3
        for (int i = 0; i < imax; ++i) {
            uint4 kvn;
            LOADKV(i + 3, kvn);

            float p = dotqk2(kv0.x, kv0.y, qf);
            p += __shfl_xor(p, 1);
            p += __shfl_xor(p, 2);
            p += __shfl_xor(p, 4);
            p = (2 * i + half < deg) ? p : -2e30f;   // tail mask

            float w[8];
            dec8v(kv0.z, kv0.w, w);
            if (__all(p - m <= 8.f)) {
                // defer-max fast path: no rescale (P bounded by e^8)
                float e = __expf(p - m);
                l += e;
                #pragma unroll
                for (int j = 0; j < 8; ++j) a[j] = fmaf(e, w[j], a[j]);
            } else {
                float nm = fmaxf(m, p);
                float c = __expf(m - nm);
                float e = __expf(p - nm);
                m = nm;
                l = l * c + e;
                #pragma unroll
                for (int j = 0; j < 8; ++j) a[j] = fmaf(e, w[j], a[j] * c);
            }

            kv0 = kv1; kv1 = kv2; kv2 = kvn;
        }
        #undef LOADKV
#else
        const u8* kvbase = kvb + hl * 32;
        #define LOADKV(I, K, V) { \
            int _ix = min(s0 + 2 * (I) + half, s1 - 1); \
            int _s = csr[_ix]; \
            K = *(const int4*)(kvbase + (size_t)_s * 1024); \
            V = *(const int4*)(kvbase + (size_t)_s * 1024 + 16); }

        int4 k0, k1, k2, v0, v1, v2;
        LOADKV(0, k0, v0);
        LOADKV(1, k1, v1);
        LOADKV(2, k2, v2);

        #pragma unroll 3
        for (int i = 0; i < imax; ++i) {
            int4 kn, vn;
            LOADKV(i + 3, kn, vn);

            float p = dotqk_h(k0, qf);
            p += __shfl_xor(p, 1);
            p += __shfl_xor(p, 2);
            p += __shfl_xor(p, 4);
            p = (2 * i + half < deg) ? p : -2e30f;

            float w[8];
            dec8_h(v0, w);
            if (__all(p - m <= 8.f)) {
                float e = __expf(p - m);
                l += e;
                #pragma unroll
                for (int j = 0; j < 8; ++j) a[j] = fmaf(e, w[j], a[j]);
            } else {
                float nm = fmaxf(m, p);
                float c = __expf(m - nm);
                float e = __expf(p - nm);
                m = nm;
                l = l * c + e;
                #pragma unroll
                for (int j = 0; j < 8; ++j) a[j] = fmaf(e, w[j], a[j] * c);
            }

            k0 = k1; v0 = v1; k1 = k2; v1 = v2; k2 = kn; v2 = vn;
        }
        #undef LOADKV
#endif
    }

    // merge the two streams (lane ^ 32 holds the partner state)
    {
        float mo = __shfl_xor(m, 32);
        float lo_ = __shfl_xor(l, 32);
        float nm = fmaxf(m, mo);
        float c  = __expf(m - nm);
        float co = __expf(mo - nm);
        l = l * c + lo_ * co;
        #pragma unroll
        for (int j = 0; j < 8; ++j) {
            float ao = __shfl_xor(a[j], 32);
            a[j] = a[j] * c + ao * co;
        }
    }

    // normalize per head, then mean over heads (hl bits 3,4)
    const float inv = 0.25f / (l + 1e-16f);
    #pragma unroll
    for (int j = 0; j < 8; ++j) {
        a[j] *= inv;
        a[j] += __shfl_xor(a[j], 8);
        a[j] += __shfl_xor(a[j], 16);
    }

    // skip connection (f16): channels c8*8 .. +7
    const int4 skw = *(const int4*)(skip + (size_t)nodeC * 64 + c8 * 8);
    f16x2 s0_ = u2h(skw.x), s1_ = u2h(skw.y), s2_ = u2h(skw.z), s3_ = u2h(skw.w);
    float o[8];
    o[0] = a[0] + (float)s0_.x; o[1] = a[1] + (float)s0_.y;
    o[2] = a[2] + (float)s1_.x; o[3] = a[3] + (float)s1_.y;
    o[4] = a[4] + (float)s2_.x; o[5] = a[5] + (float)s2_.y;
    o[6] = a[6] + (float)s3_.x; o[7] = a[7] + (float)s3_.y;

    // LayerNorm over 64 channels (8 lanes x 8 ch within each 8-lane group)
    float s = o[0] + o[1] + o[2] + o[3] + o[4] + o[5] + o[6] + o[7];
    s += __shfl_xor(s, 1); s += __shfl_xor(s, 2); s += __shfl_xor(s, 4);
    const float mu = s * (1.f / 64.f);
    float vs = 0.f;
    #pragma unroll
    for (int j = 0; j < 8; ++j) { o[j] -= mu; vs = fmaf(o[j], o[j], vs); }
    vs += __shfl_xor(vs, 1); vs += __shfl_xor(vs, 2); vs += __shfl_xor(vs, 4);
    const float rs = rsqrtf(vs * (1.f / 64.f) + 1e-5f);

    const float4* gp = (const float4*)(lng + c8 * 8);
    const float4* bp = (const float4*)(lnb + c8 * 8);
    float4 g0 = gp[0], g1 = gp[1], b0 = bp[0], b1 = bp[1];
    float y[8];
    y[0] = o[0] * rs * g0.x + b0.x; y[1] = o[1] * rs * g0.y + b0.y;
    y[2] = o[2] * rs * g0.z + b0.z; y[3] = o[3] * rs * g0.w + b0.w;
    y[4] = o[4] * rs * g1.x + b1.x; y[5] = o[5] * rs * g1.y + b1.y;
    y[6] = o[6] * rs * g1.z + b1.z; y[7] = o[7] * rs * g1.w + b1.w;
    if (RELU) {
        #pragma unroll
        for (int j = 0; j < 8; ++j) y[j] = fmaxf(y[j], 0.f);
    }

    if (FINAL) {
        // fused 64->32 matvec via LDS (y of 4 nodes staged per block)
        __shared__ float yl[4][64];
        if (lane < 8) {
            #pragma unroll
            for (int j = 0; j < 8; ++j) yl[wv][c8 * 8 + j] = y[j];
        }
        __syncthreads();
        int t = threadIdx.x;
        if (t < 128) {
            int nd = t >> 5, oc = t & 31;
            int gn = blockIdx.x * 4 + nd;
            if (gn < n) {
                float acc = bfv[oc];
                #pragma unroll
                for (int c = 0; c < 64; ++c)
                    acc = fmaf(yl[nd][c], Wf[c * 32 + oc], acc);
                outF[(size_t)gn * 32 + oc] = acc;
            }
        }
    } else if (lane < 8 && nvalid) {
        if (BF16OUT) {
            bf16x8 ob;
            #pragma unroll
            for (int j = 0; j < 8; ++j) ob[j] = (short)f2bf(y[j]);
            *(bf16x8*)(out_bf + (size_t)node * 64 + c8 * 8) = ob;
        }
    }
}

// ---------------------------------------------------------------------------
extern "C" void kernel_launch(void* const* d_in, const int* in_sizes, int n_in,
                              void* d_out, int out_size, void* d_ws, size_t ws_size,
                              hipStream_t stream)
{
    const float* x   = (const float*)d_in[0];
    const int*   ei  = (const int*)d_in[1];
    const float* Wq1 = (const float*)d_in[2];  const float* bq1 = (const float*)d_in[3];
    const float* Wk1 = (const float*)d_in[4];  const float* bk1 = (const float*)d_in[5];
    const float* Wv1 = (const float*)d_in[6];  const float* bv1 = (const float*)d_in[7];
    const float* Ws1 = (const float*)d_in[8];  const float* bs1 = (const float*)d_in[9];
    const float* Wq2 = (const float*)d_in[10]; const float* bq2 = (const float*)d_in[11];
    const float* Wk2 = (const float*)d_in[12]; const float* bk2 = (const float*)d_in[13];
    const float* Wv2 = (const float*)d_in[14]; const float* bv2 = (const float*)d_in[15];
    const float* Ws2 = (const float*)d_in[16]; const float* bs2 = (const float*)d_in[17];
    const float* lng = (const float*)d_in[18]; const float* lnb = (const float*)d_in[19];
    const float* Wf  = (const float*)d_in[20]; const float* bf  = (const float*)d_in[21];

    const int N = in_sizes[0] / 64;
    const int E = in_sizes[1] / 2;
    const int* src  = ei;
    const int* dstp = ei + E;

    char* p = (char*)d_ws;
    u16* qb   = (u16*)p; p += (size_t)N * 256 * 2;   // f16
    u8*  kvb  = (u8*)p;  p += (size_t)N * 1024;      // fp8 interleaved (f16 fallback fits)
    u16* xbf  = (u16*)p; p += (size_t)N * 64 * 2;    // conv1 output h (bf16)
    u16* wt1  = (u16*)p; p += 832 * 64 * 2;
    u16* wt2  = (u16*)p; p += 832 * 64 * 2;
    float* ba1  = (float*)p; p += 832 * 4;
    float* ba2  = (float*)p; p += 832 * 4;
    u16* skip = (u16*)p; p += (size_t)N * 64 * 2;    // f16
    int* deg    = (int*)p; p += (size_t)N * 4;
    int* off    = (int*)p; p += ((size_t)N + 1) * 4;
    int* cursor = (int*)p; p += (size_t)N * 4;
    int* csr    = (int*)p; p += (size_t)E * 4;
    int* bsum   = (int*)p; p += 1024;
    int* bpre   = (int*)p; p += 1024;

    const int e_blocks    = (E + 255) / 256;
    const int n_blocks    = (N + 255) / 256;
    const int prep_blocks = 416 + n_blocks;
    const int gb          = (N + 31) / 32;          // 32 nodes/block
    const int attn_blocks = (N + 3) / 4;            // 1 node/wave, 4 waves/blk

    // ---- prep: fused conversions + zero deg ----
    prep_misc<<<prep_blocks, 256, 0, stream>>>(
        Wq1, Wk1, Wv1, Ws1, bq1, bk1, bv1, bs1,
        Wq2, Wk2, Wv2, Ws2, bq2, bk2, bv2, bs2,
        wt1, ba1, wt2, ba2, deg, N);

    // ---- conv1 GEMM + degree histogram (fused, both only need prep) ----
    gemm1_hist<<<gb + e_blocks, 256, 0, stream>>>(
        x, wt1, ba1, qb, kvb, skip, N, dstp, deg, E, gb);

    // ---- CSR scan + fill ----
    scanA<<<n_blocks, 256, 0, stream>>>(deg, bsum, N);
    scanB<<<1, 256, 0, stream>>>(bsum, bpre, n_blocks);
    scanC<<<n_blocks, 256, 0, stream>>>(deg, bpre, off, cursor, N, E);
    fill_kernel<<<e_blocks, 256, 0, stream>>>(src, dstp, cursor, csr, E);

    // ---- conv1 attention (writes h bf16) ----
    fused_attn<1, 1, 0><<<attn_blocks, 256, 0, stream>>>(
        qb, kvb, skip, off, csr, lng, lnb, xbf, nullptr, nullptr, nullptr, N);

    // ---- conv2 GEMM ----
    gemm_qkvs2<<<gb, 256, 0, stream>>>(xbf, wt2, ba2, qb, kvb, skip, N);

    // ---- conv2 attention + fused final LN/Linear -> d_out ----
    fused_attn<0, 0, 1><<<attn_blocks, 256, 0, stream>>>(
        qb, kvb, skip, off, csr, lng, lnb, nullptr, Wf, bf, (float*)d_out, N);
}

// Round 17
// 322.397 us; speedup vs baseline: 1.3105x; 1.0400x over previous
//
#include <hip/hip_runtime.h>
#include <hip/hip_bf16.h>
#include <math.h>

typedef unsigned short u16;
typedef unsigned char u8;
typedef __attribute__((ext_vector_type(8))) short bf16x8;
typedef __attribute__((ext_vector_type(4))) float f32x4;
typedef __attribute__((ext_vector_type(2))) float f32x2;
typedef _Float16 f16;
typedef __attribute__((ext_vector_type(2))) _Float16 f16x2;

#if __has_builtin(__builtin_amdgcn_cvt_pk_f32_fp8) && __has_builtin(__builtin_amdgcn_cvt_pk_fp8_f32)
#define HAS_FP8 1
#else
#define HAS_FP8 0
#endif

#if __has_builtin(__builtin_elementwise_fma)
#define VFMA(a, b, c) __builtin_elementwise_fma((a), (b), (c))
#else
#define VFMA(a, b, c) ((a) * (b) + (c))   // HIP default contracts to fma
#endif

__device__ __forceinline__ u16 f2bf(float f) {
    unsigned u = __float_as_uint(f);
    u += 0x7fffu + ((u >> 16) & 1u);   // RNE
    return (u16)(u >> 16);
}
__device__ __forceinline__ u16 f2h(float f) {
    return __builtin_bit_cast(u16, (f16)f);   // v_cvt_f16_f32 (RNE)
}
__device__ __forceinline__ f16x2 u2h(int u) {
    return __builtin_bit_cast(f16x2, u);
}
__device__ __forceinline__ f32x2 shfl_xor2(f32x2 v, int mask) {
    double d = __builtin_bit_cast(double, v);
    d = __shfl_xor(d, mask);
    return __builtin_bit_cast(f32x2, d);
}
__device__ __forceinline__ f32x2 mk2(float a, float b) {
    f32x2 r; r.x = a; r.y = b; return r;
}

// ---------------------------------------------------------------------------
// prep_misc: grid-partitioned fusion of {convert W1, convert W2, zero deg}.
// wt[832][64] bf16 (cols 0-255 q *0.125 folded, 256-511 k, 512-767 v,
// 768-831 s), bias ba[832] fp32 (q part *0.125).
// ---------------------------------------------------------------------------
__device__ __forceinline__ void conv_w_one(
    int idx,
    const float* __restrict__ Wq, const float* __restrict__ Wk,
    const float* __restrict__ Wv, const float* __restrict__ Ws,
    const float* __restrict__ bq, const float* __restrict__ bk,
    const float* __restrict__ bv, const float* __restrict__ bs,
    u16* __restrict__ wt, float* __restrict__ ba)
{
    int col = idx >> 6, k = idx & 63;
    float w;
    if      (col < 256) w = Wq[k * 256 + col] * 0.125f;          // fold 1/sqrt(C)
    else if (col < 512) w = Wk[k * 256 + (col - 256)];
    else if (col < 768) w = Wv[k * 256 + (col - 512)];
    else                w = Ws[k * 64  + (col - 768)];
    wt[col * 64 + k] = f2bf(w);
    if (k == 0)
        ba[col] = (col < 256) ? bq[col] * 0.125f : (col < 512) ? bk[col - 256]
                 : (col < 768) ? bv[col - 512] : bs[col - 768];
}

__global__ __launch_bounds__(256) void prep_misc(
    const float* __restrict__ Wq1, const float* __restrict__ Wk1,
    const float* __restrict__ Wv1, const float* __restrict__ Ws1,
    const float* __restrict__ bq1, const float* __restrict__ bk1,
    const float* __restrict__ bv1, const float* __restrict__ bs1,
    const float* __restrict__ Wq2, const float* __restrict__ Wk2,
    const float* __restrict__ Wv2, const float* __restrict__ Ws2,
    const float* __restrict__ bq2, const float* __restrict__ bk2,
    const float* __restrict__ bv2, const float* __restrict__ bs2,
    u16* __restrict__ wt1, float* __restrict__ ba1,
    u16* __restrict__ wt2, float* __restrict__ ba2,
    int* __restrict__ deg, int n)
{
    int b = blockIdx.x, t = threadIdx.x;
    if (b < 208) {
        conv_w_one(b * 256 + t, Wq1, Wk1, Wv1, Ws1, bq1, bk1, bv1, bs1, wt1, ba1);
    } else if (b < 416) {
        conv_w_one((b - 208) * 256 + t, Wq2, Wk2, Wv2, Ws2, bq2, bk2, bv2, bs2, wt2, ba2);
    } else {
        int i = (b - 416) * 256 + t;
        if (i < n) deg[i] = 0;
    }
}

// ---------------------------------------------------------------------------
// CSR scan (3-phase coalesced) + fill
// ---------------------------------------------------------------------------
__global__ __launch_bounds__(256) void scanA(
    const int* __restrict__ deg, int* __restrict__ bsum, int n)
{
    int i = blockIdx.x * 256 + threadIdx.x;
    int v = (i < n) ? deg[i] : 0;
    #pragma unroll
    for (int o = 32; o; o >>= 1) v += __shfl_xor(v, o);
    __shared__ int wsum[4];
    if ((threadIdx.x & 63) == 0) wsum[threadIdx.x >> 6] = v;
    __syncthreads();
    if (threadIdx.x == 0)
        bsum[blockIdx.x] = wsum[0] + wsum[1] + wsum[2] + wsum[3];
}

__global__ __launch_bounds__(256) void scanB(
    const int* __restrict__ bsum, int* __restrict__ bpre, int nb)
{
    int t = threadIdx.x;
    int v = (t < nb) ? bsum[t] : 0;
    int lane = t & 63, wv = t >> 6;
    int sv = v;
    #pragma unroll
    for (int o = 1; o < 64; o <<= 1) {
        int u = __shfl_up(sv, o);
        if (lane >= o) sv += u;
    }
    __shared__ int wsum[4];
    if (lane == 63) wsum[wv] = sv;
    __syncthreads();
    int add = 0;
    for (int k = 0; k < wv; ++k) add += wsum[k];
    if (t < nb) bpre[t] = sv + add - v;   // exclusive
}

__global__ __launch_bounds__(256) void scanC(
    const int* __restrict__ deg, const int* __restrict__ bpre,
    int* __restrict__ off, int* __restrict__ cursor, int n, int E)
{
    int i = blockIdx.x * 256 + threadIdx.x;
    int v = (i < n) ? deg[i] : 0;
    int lane = threadIdx.x & 63, wv = threadIdx.x >> 6;
    int sv = v;
    #pragma unroll
    for (int o = 1; o < 64; o <<= 1) {
        int u = __shfl_up(sv, o);
        if (lane >= o) sv += u;
    }
    __shared__ int wsum[4];
    if (lane == 63) wsum[wv] = sv;
    __syncthreads();
    int add = bpre[blockIdx.x];
    for (int k = 0; k < wv; ++k) add += wsum[k];
    int excl = add + sv - v;
    if (i < n) {
        off[i] = excl; cursor[i] = excl;
        if (i == n - 1) off[n] = E;
    }
}

__global__ __launch_bounds__(256) void fill_kernel(
    const int* __restrict__ src, const int* __restrict__ dst,
    int* __restrict__ cursor, int* __restrict__ csr_src, int E)
{
    int e = blockIdx.x * 256 + threadIdx.x;
    if (e >= E) return;
    int slot = atomicAdd(&cursor[dst[e]], 1);
    csr_src[slot] = src[e];
}

// ---------------------------------------------------------------------------
// bf16 MFMA GEMM body: 32 nodes/block (two B-fragment groups share the same
// A/wt fragments). Each lane owns 4 consecutive output cols. q f16; k,v fp8
// INTERLEAVED in kvb (per node: 32 lane-groups x {8B k, 8B v}); skip f16.
// ---------------------------------------------------------------------------
template <int FP32IN>
__device__ __forceinline__ void gemm_body(
    int blk, const void* __restrict__ Xv, const u16* __restrict__ wt,
    const float* __restrict__ ba,
    u16* __restrict__ qb, u8* __restrict__ kvb, u16* __restrict__ skip, int n)
{
    const int w = threadIdx.x >> 6, lane = threadIdx.x & 63;
    const int r = lane & 15, g = lane >> 4;
    const int node0 = blk * 32;

    bf16x8 bx0[2], bx1[2];                    // X fragments, 2 node groups
    #pragma unroll
    for (int grp = 0; grp < 2; ++grp) {
        int nr = node0 + grp * 16 + r; if (nr >= n) nr = n - 1;
        if (FP32IN) {
            const float* xr = (const float*)Xv + (size_t)nr * 64 + g * 8;
            float t0[8], t1[8];
            *(float4*)(t0)     = ((const float4*)xr)[0];
            *(float4*)(t0 + 4) = ((const float4*)xr)[1];
            *(float4*)(t1)     = ((const float4*)(xr + 32))[0];
            *(float4*)(t1 + 4) = ((const float4*)(xr + 32))[1];
            #pragma unroll
            for (int j = 0; j < 8; ++j) {
                bx0[grp][j] = (short)f2bf(t0[j]);
                bx1[grp][j] = (short)f2bf(t1[j]);
            }
        } else {
            const u16* xr = (const u16*)Xv + (size_t)nr * 64 + g * 8;
            bx0[grp] = *(const bf16x8*)xr;
            bx1[grp] = *(const bf16x8*)(xr + 32);
        }
    }

    const int colbase = w * 208;

    const u16* wr0 = wt + (size_t)(colbase + r) * 64 + g * 8;
    bf16x8 a0 = *(const bf16x8*)wr0;
    bf16x8 a1 = *(const bf16x8*)(wr0 + 32);

    for (int ct = 0; ct < 13; ++ct) {
        int ctn = (ct + 1 < 13) ? ct + 1 : 12;
        const u16* wrn = wt + (size_t)(colbase + ctn * 16 + r) * 64 + g * 8;
        bf16x8 an0 = *(const bf16x8*)wrn;
        bf16x8 an1 = *(const bf16x8*)(wrn + 32);

        int col0 = colbase + ct * 16 + g * 4;
        float4 bias = *(const float4*)(ba + col0);

        #pragma unroll
        for (int grp = 0; grp < 2; ++grp) {
            f32x4 acc = {0.f, 0.f, 0.f, 0.f};
            acc = __builtin_amdgcn_mfma_f32_16x16x32_bf16(a0, bx0[grp], acc, 0, 0, 0);
            acc = __builtin_amdgcn_mfma_f32_16x16x32_bf16(a1, bx1[grp], acc, 0, 0, 0);
            int node = node0 + grp * 16 + r;
            if (node < n) {
                float v0 = acc[0] + bias.x, v1 = acc[1] + bias.y;
                float v2 = acc[2] + bias.z, v3 = acc[3] + bias.w;
                if (col0 < 256) {
                    ushort4 o;
                    o.x = f2h(v0); o.y = f2h(v1); o.z = f2h(v2); o.w = f2h(v3);
                    *(ushort4*)(qb + (size_t)node * 256 + col0) = o;
                } else if (col0 < 768) {
                    const bool isK = col0 < 512;
                    int c = col0 - (isK ? 256 : 512);
#if HAS_FP8
                    unsigned pk = __builtin_amdgcn_cvt_pk_fp8_f32(v0, v1, 0u, false);
                    pk = __builtin_amdgcn_cvt_pk_fp8_f32(v2, v3, pk, true);
                    *(unsigned*)(kvb + (size_t)node * 512 + ((c >> 3) << 4)
                                 + (c & 7) + (isK ? 0 : 8)) = pk;
#else
                    ushort4 o;
                    o.x = f2h(v0); o.y = f2h(v1); o.z = f2h(v2); o.w = f2h(v3);
                    *(ushort4*)(kvb + (size_t)node * 1024 + ((c >> 3) << 5)
                                + ((c & 7) << 1) + (isK ? 0 : 16)) = o;
#endif
                } else {
                    ushort4 o;
                    o.x = f2h(v0); o.y = f2h(v1); o.z = f2h(v2); o.w = f2h(v3);
                    *(ushort4*)(skip + (size_t)node * 64 + (col0 - 768)) = o;
                }
            }
        }
        a0 = an0; a1 = an1;
    }
}

// gemm1 fused with degree histogram (both depend only on prep_misc)
__global__ __launch_bounds__(256) void gemm1_hist(
    const float* __restrict__ x, const u16* __restrict__ wt,
    const float* __restrict__ ba,
    u16* __restrict__ qb, u8* __restrict__ kvb, u16* __restrict__ skip, int n,
    const int* __restrict__ dst, int* __restrict__ deg, int E, int gb)
{
    int b = blockIdx.x;
    if (b < gb) {
        gemm_body<1>(b, x, wt, ba, qb, kvb, skip, n);
    } else {
        int e = (b - gb) * 256 + threadIdx.x;
        if (e < E) atomicAdd(&deg[dst[e]], 1);
    }
}

__global__ __launch_bounds__(256) void gemm_qkvs2(
    const u16* __restrict__ xbf, const u16* __restrict__ wt,
    const float* __restrict__ ba,
    u16* __restrict__ qb, u8* __restrict__ kvb, u16* __restrict__ skip, int n)
{
    gemm_body<0>(blockIdx.x, xbf, wt, ba, qb, kvb, skip, n);
}

// ---------------------------------------------------------------------------
// Fused attention: ONE node per wave, TWO edge-streams (half-wave each,
// edges t = 2i+half). Interleaved fp8 kv: ONE dwordx4 gather per lane per
// iteration. PACKED f32x2 math throughout (v_pk_fma_f32): dot = 4 pk_fma,
// PV = 4 pk_fma, epilogue reduces via 64-bit shuffles. defer-max (THR=8),
// clamped 3-deep prefetch ring under #pragma unroll 3.
// FINAL: fuse LayerNorm output through LDS into the 64->32 matvec (d_out).
// ---------------------------------------------------------------------------
template <int RELU, int BF16OUT, int FINAL>
__global__ __launch_bounds__(256) void fused_attn(
    const u16* __restrict__ qb, const u8* __restrict__ kvb,
    const u16* __restrict__ skip,
    const int* __restrict__ off, const int* __restrict__ csr,
    const float* __restrict__ lng, const float* __restrict__ lnb,
    u16* __restrict__ out_bf,
    const float* __restrict__ Wf, const float* __restrict__ bfv,
    float* __restrict__ outF, int n)
{
    const int lane = threadIdx.x & 63;
    const int half = lane >> 5;          // edge-stream parity
    const int hl   = lane & 31;          // h*8 + c8
    const int c8   = lane & 7;
    const int wv   = threadIdx.x >> 6;
    const int node = blockIdx.x * 4 + wv;
    const bool nvalid = node < n;
    const int nodeC = nvalid ? node : n - 1;

    // q: decode f16 row slice to packed f32x2 (1/sqrt(C) pre-folded into Wq)
    const int4 qw = *(const int4*)(qb + (size_t)nodeC * 256 + hl * 8);
    f32x2 q01, q23, q45, q67;
    {
        f16x2 t0 = u2h(qw.x), t1 = u2h(qw.y), t2 = u2h(qw.z), t3 = u2h(qw.w);
        q01 = mk2((float)t0.x, (float)t0.y);
        q23 = mk2((float)t1.x, (float)t1.y);
        q45 = mk2((float)t2.x, (float)t2.y);
        q67 = mk2((float)t3.x, (float)t3.y);
    }

    const int s0 = off[nodeC], s1 = off[nodeC + 1];
    const int deg = nvalid ? (s1 - s0) : 0;
    const int imax = (deg + 1) >> 1;     // iterations per stream

    float m = -1e30f, l = 0.f;
    f32x2 a01 = mk2(0.f, 0.f), a23 = mk2(0.f, 0.f);
    f32x2 a45 = mk2(0.f, 0.f), a67 = mk2(0.f, 0.f);

    if (imax > 0) {
#if HAS_FP8
        const u8* kvbase = kvb + hl * 16;
        // clamped: tail loads re-read row csr[s1-1] (cache-hot, masked out)
        #define LOADKV(I, KV) { \
            int _ix = min(s0 + 2 * (I) + half, s1 - 1); \
            int _s = csr[_ix]; \
            KV = *(const uint4*)(kvbase + (size_t)_s * 512); }

        uint4 kv0, kv1, kv2;
        LOADKV(0, kv0);
        LOADKV(1, kv1);
        LOADKV(2, kv2);

        #pragma unroll 3
        for (int i = 0; i < imax; ++i) {
            uint4 kvn;
            LOADKV(i + 3, kvn);

            f32x2 k01 = __builtin_amdgcn_cvt_pk_f32_fp8(kv0.x, false);
            f32x2 k23 = __builtin_amdgcn_cvt_pk_f32_fp8(kv0.x, true);
            f32x2 k45 = __builtin_amdgcn_cvt_pk_f32_fp8(kv0.y, false);
            f32x2 k67 = __builtin_amdgcn_cvt_pk_f32_fp8(kv0.y, true);
            f32x2 pp = k01 * q01;
            pp = VFMA(k23, q23, pp);
            pp = VFMA(k45, q45, pp);
            pp = VFMA(k67, q67, pp);
            float p = pp.x + pp.y;
            p += __shfl_xor(p, 1);
            p += __shfl_xor(p, 2);
            p += __shfl_xor(p, 4);
            p = (2 * i + half < deg) ? p : -2e30f;   // tail mask

            f32x2 w01 = __builtin_amdgcn_cvt_pk_f32_fp8(kv0.z, false);
            f32x2 w23 = __builtin_amdgcn_cvt_pk_f32_fp8(kv0.z, true);
            f32x2 w45 = __builtin_amdgcn_cvt_pk_f32_fp8(kv0.w, false);
            f32x2 w67 = __builtin_amdgcn_cvt_pk_f32_fp8(kv0.w, true);
            if (__all(p - m <= 8.f)) {
                // defer-max fast path: no rescale (P bounded by e^8)
                float e = __expf(p - m);
                l += e;
                f32x2 e2 = mk2(e, e);
                a01 = VFMA(e2, w01, a01);
                a23 = VFMA(e2, w23, a23);
                a45 = VFMA(e2, w45, a45);
                a67 = VFMA(e2, w67, a67);
            } else {
                float nm = fmaxf(m, p);
                float c = __expf(m - nm);
                float e = __expf(p - nm);
                m = nm;
                l = l * c + e;
                f32x2 e2 = mk2(e, e), c2 = mk2(c, c);
                a01 = VFMA(e2, w01, a01 * c2);
                a23 = VFMA(e2, w23, a23 * c2);
                a45 = VFMA(e2, w45, a45 * c2);
                a67 = VFMA(e2, w67, a67 * c2);
            }

            kv0 = kv1; kv1 = kv2; kv2 = kvn;
        }
        #undef LOADKV
#else
        const u8* kvbase = kvb + hl * 32;
        #define LOADKV(I, K, V) { \
            int _ix = min(s0 + 2 * (I) + half, s1 - 1); \
            int _s = csr[_ix]; \
            K = *(const int4*)(kvbase + (size_t)_s * 1024); \
            V = *(const int4*)(kvbase + (size_t)_s * 1024 + 16); }

        int4 k0, k1, k2, v0, v1, v2;
        LOADKV(0, k0, v0);
        LOADKV(1, k1, v1);
        LOADKV(2, k2, v2);

        #pragma unroll 3
        for (int i = 0; i < imax; ++i) {
            int4 kn, vn;
            LOADKV(i + 3, kn, vn);

            f16x2 t0 = u2h(k0.x), t1 = u2h(k0.y), t2 = u2h(k0.z), t3 = u2h(k0.w);
            f32x2 k01 = mk2((float)t0.x, (float)t0.y);
            f32x2 k23 = mk2((float)t1.x, (float)t1.y);
            f32x2 k45 = mk2((float)t2.x, (float)t2.y);
            f32x2 k67 = mk2((float)t3.x, (float)t3.y);
            f32x2 pp = k01 * q01;
            pp = VFMA(k23, q23, pp);
            pp = VFMA(k45, q45, pp);
            pp = VFMA(k67, q67, pp);
            float p = pp.x + pp.y;
            p += __shfl_xor(p, 1);
            p += __shfl_xor(p, 2);
            p += __shfl_xor(p, 4);
            p = (2 * i + half < deg) ? p : -2e30f;

            f16x2 s0v = u2h(v0.x), s1v = u2h(v0.y), s2v = u2h(v0.z), s3v = u2h(v0.w);
            f32x2 w01 = mk2((float)s0v.x, (float)s0v.y);
            f32x2 w23 = mk2((float)s1v.x, (float)s1v.y);
            f32x2 w45 = mk2((float)s2v.x, (float)s2v.y);
            f32x2 w67 = mk2((float)s3v.x, (float)s3v.y);
            if (__all(p - m <= 8.f)) {
                float e = __expf(p - m);
                l += e;
                f32x2 e2 = mk2(e, e);
                a01 = VFMA(e2, w01, a01);
                a23 = VFMA(e2, w23, a23);
                a45 = VFMA(e2, w45, a45);
                a67 = VFMA(e2, w67, a67);
            } else {
                float nm = fmaxf(m, p);
                float c = __expf(m - nm);
                float e = __expf(p - nm);
                m = nm;
                l = l * c + e;
                f32x2 e2 = mk2(e, e), c2 = mk2(c, c);
                a01 = VFMA(e2, w01, a01 * c2);
                a23 = VFMA(e2, w23, a23 * c2);
                a45 = VFMA(e2, w45, a45 * c2);
                a67 = VFMA(e2, w67, a67 * c2);
            }

            k0 = k1; v0 = v1; k1 = k2; v1 = v2; k2 = kn; v2 = vn;
        }
        #undef LOADKV
#endif
    }

    // merge the two streams (lane ^ 32 holds the partner state)
    {
        float mo = __shfl_xor(m, 32);
        float lo_ = __shfl_xor(l, 32);
        float nm = fmaxf(m, mo);
        float c  = __expf(m - nm);
        float co = __expf(mo - nm);
        l = l * c + lo_ * co;
        f32x2 c2 = mk2(c, c), co2 = mk2(co, co);
        f32x2 t;
        t = shfl_xor2(a01, 32); a01 = VFMA(t, co2, a01 * c2);
        t = shfl_xor2(a23, 32); a23 = VFMA(t, co2, a23 * c2);
        t = shfl_xor2(a45, 32); a45 = VFMA(t, co2, a45 * c2);
        t = shfl_xor2(a67, 32); a67 = VFMA(t, co2, a67 * c2);
    }

    // normalize per head, then mean over heads (hl bits 3,4)
    {
        const float inv = 0.25f / (l + 1e-16f);
        f32x2 inv2 = mk2(inv, inv);
        a01 *= inv2; a23 *= inv2; a45 *= inv2; a67 *= inv2;
        a01 = a01 + shfl_xor2(a01, 8);  a01 = a01 + shfl_xor2(a01, 16);
        a23 = a23 + shfl_xor2(a23, 8);  a23 = a23 + shfl_xor2(a23, 16);
        a45 = a45 + shfl_xor2(a45, 8);  a45 = a45 + shfl_xor2(a45, 16);
        a67 = a67 + shfl_xor2(a67, 8);  a67 = a67 + shfl_xor2(a67, 16);
    }

    // skip connection (f16): channels c8*8 .. +7
    const int4 skw = *(const int4*)(skip + (size_t)nodeC * 64 + c8 * 8);
    f16x2 s0_ = u2h(skw.x), s1_ = u2h(skw.y), s2_ = u2h(skw.z), s3_ = u2h(skw.w);
    f32x2 o01 = a01 + mk2((float)s0_.x, (float)s0_.y);
    f32x2 o23 = a23 + mk2((float)s1_.x, (float)s1_.y);
    f32x2 o45 = a45 + mk2((float)s2_.x, (float)s2_.y);
    f32x2 o67 = a67 + mk2((float)s3_.x, (float)s3_.y);

    // LayerNorm over 64 channels (8 lanes x 8 ch within each 8-lane group)
    f32x2 ss = o01 + o23 + o45 + o67;
    float s = ss.x + ss.y;
    s += __shfl_xor(s, 1); s += __shfl_xor(s, 2); s += __shfl_xor(s, 4);
    const float mu = s * (1.f / 64.f);
    f32x2 mu2 = mk2(mu, mu);
    o01 -= mu2; o23 -= mu2; o45 -= mu2; o67 -= mu2;
    f32x2 vv = o01 * o01;
    vv = VFMA(o23, o23, vv);
    vv = VFMA(o45, o45, vv);
    vv = VFMA(o67, o67, vv);
    float vs = vv.x + vv.y;
    vs += __shfl_xor(vs, 1); vs += __shfl_xor(vs, 2); vs += __shfl_xor(vs, 4);
    const float rs = rsqrtf(vs * (1.f / 64.f) + 1e-5f);
    f32x2 rs2 = mk2(rs, rs);

    const float4* gp = (const float4*)(lng + c8 * 8);
    const float4* bp = (const float4*)(lnb + c8 * 8);
    float4 g0 = gp[0], g1 = gp[1], b0 = bp[0], b1 = bp[1];
    f32x2 g01 = mk2(g0.x, g0.y), g23 = mk2(g0.z, g0.w);
    f32x2 g45 = mk2(g1.x, g1.y), g67 = mk2(g1.z, g1.w);
    f32x2 bb01 = mk2(b0.x, b0.y), bb23 = mk2(b0.z, b0.w);
    f32x2 bb45 = mk2(b1.x, b1.y), bb67 = mk2(b1.z, b1.w);
    f32x2 y01 = VFMA(o01 * rs2, g01, bb01);
    f32x2 y23 = VFMA(o23 * rs2, g23, bb23);
    f32x2 y45 = VFMA(o45 * rs2, g45, bb45);
    f32x2 y67 = VFMA(o67 * rs2, g67, bb67);
    if (RELU) {
        y01 = mk2(fmaxf(y01.x, 0.f), fmaxf(y01.y, 0.f));
        y23 = mk2(fmaxf(y23.x, 0.f), fmaxf(y23.y, 0.f));
        y45 = mk2(fmaxf(y45.x, 0.f), fmaxf(y45.y, 0.f));
        y67 = mk2(fmaxf(y67.x, 0.f), fmaxf(y67.y, 0.f));
    }

    if (FINAL) {
        // fused 64->32 matvec via LDS (y of 4 nodes staged per block)
        __shared__ float yl[4][64];
        if (lane < 8) {
            float* dst = &yl[wv][c8 * 8];
            *(float2*)(dst + 0) = make_float2(y01.x, y01.y);
            *(float2*)(dst + 2) = make_float2(y23.x, y23.y);
            *(float2*)(dst + 4) = make_float2(y45.x, y45.y);
            *(float2*)(dst + 6) = make_float2(y67.x, y67.y);
        }
        __syncthreads();
        int t = threadIdx.x;
        if (t < 128) {
            int nd = t >> 5, oc = t & 31;
            int gn = blockIdx.x * 4 + nd;
            if (gn < n) {
                float acc = bfv[oc];
                #pragma unroll
                for (int c = 0; c < 64; ++c)
                    acc = fmaf(yl[nd][c], Wf[c * 32 + oc], acc);
                outF[(size_t)gn * 32 + oc] = acc;
            }
        }
    } else if (lane < 8 && nvalid) {
        if (BF16OUT) {
            bf16x8 ob;
            ob[0] = (short)f2bf(y01.x); ob[1] = (short)f2bf(y01.y);
            ob[2] = (short)f2bf(y23.x); ob[3] = (short)f2bf(y23.y);
            ob[4] = (short)f2bf(y45.x); ob[5] = (short)f2bf(y45.y);
            ob[6] = (short)f2bf(y67.x); ob[7] = (short)f2bf(y67.y);
            *(bf16x8*)(out_bf + (size_t)node * 64 + c8 * 8) = ob;
        }
    }
}

// ---------------------------------------------------------------------------
extern "C" void kernel_launch(void* const* d_in, const int* in_sizes, int n_in,
                              void* d_out, int out_size, void* d_ws, size_t ws_size,
                              hipStream_t stream)
{
    const float* x   = (const float*)d_in[0];
    const int*   ei  = (const int*)d_in[1];
    const float* Wq1 = (const float*)d_in[2];  const float* bq1 = (const float*)d_in[3];
    const float* Wk1 = (const float*)d_in[4];  const float* bk1 = (const float*)d_in[5];
    const float* Wv1 = (const float*)d_in[6];  const float* bv1 = (const float*)d_in[7];
    const float* Ws1 = (const float*)d_in[8];  const float* bs1 = (const float*)d_in[9];
    const float* Wq2 = (const float*)d_in[10]; const float* bq2 = (const float*)d_in[11];
    const float* Wk2 = (const float*)d_in[12]; const float* bk2 = (const float*)d_in[13];
    const float* Wv2 = (const float*)d_in[14]; const float* bv2 = (const float*)d_in[15];
    const float* Ws2 = (const float*)d_in[16]; const float* bs2 = (const float*)d_in[17];
    const float* lng = (const float*)d_in[18]; const float* lnb = (const float*)d_in[19];
    const float* Wf  = (const float*)d_in[20]; const float* bf  = (const float*)d_in[21];

    const int N = in_sizes[0] / 64;
    const int E = in_sizes[1] / 2;
    const int* src  = ei;
    const int* dstp = ei + E;

    char* p = (char*)d_ws;
    u16* qb   = (u16*)p; p += (size_t)N * 256 * 2;   // f16
    u8*  kvb  = (u8*)p;  p += (size_t)N * 1024;      // fp8 interleaved (f16 fallback fits)
    u16* xbf  = (u16*)p; p += (size_t)N * 64 * 2;    // conv1 output h (bf16)
    u16* wt1  = (u16*)p; p += 832 * 64 * 2;
    u16* wt2  = (u16*)p; p += 832 * 64 * 2;
    float* ba1  = (float*)p; p += 832 * 4;
    float* ba2  = (float*)p; p += 832 * 4;
    u16* skip = (u16*)p; p += (size_t)N * 64 * 2;    // f16
    int* deg    = (int*)p; p += (size_t)N * 4;
    int* off    = (int*)p; p += ((size_t)N + 1) * 4;
    int* cursor = (int*)p; p += (size_t)N * 4;
    int* csr    = (int*)p; p += (size_t)E * 4;
    int* bsum   = (int*)p; p += 1024;
    int* bpre   = (int*)p; p += 1024;

    const int e_blocks    = (E + 255) / 256;
    const int n_blocks    = (N + 255) / 256;
    const int prep_blocks = 416 + n_blocks;
    const int gb          = (N + 31) / 32;          // 32 nodes/block
    const int attn_blocks = (N + 3) / 4;            // 1 node/wave, 4 waves/blk

    // ---- prep: fused conversions + zero deg ----
    prep_misc<<<prep_blocks, 256, 0, stream>>>(
        Wq1, Wk1, Wv1, Ws1, bq1, bk1, bv1, bs1,
        Wq2, Wk2, Wv2, Ws2, bq2, bk2, bv2, bs2,
        wt1, ba1, wt2, ba2, deg, N);

    // ---- conv1 GEMM + degree histogram (fused, both only need prep) ----
    gemm1_hist<<<gb + e_blocks, 256, 0, stream>>>(
        x, wt1, ba1, qb, kvb, skip, N, dstp, deg, E, gb);

    // ---- CSR scan + fill ----
    scanA<<<n_blocks, 256, 0, stream>>>(deg, bsum, N);
    scanB<<<1, 256, 0, stream>>>(bsum, bpre, n_blocks);
    scanC<<<n_blocks, 256, 0, stream>>>(deg, bpre, off, cursor, N, E);
    fill_kernel<<<e_blocks, 256, 0, stream>>>(src, dstp, cursor, csr, E);

    // ---- conv1 attention (writes h bf16) ----
    fused_attn<1, 1, 0><<<attn_blocks, 256, 0, stream>>>(
        qb, kvb, skip, off, csr, lng, lnb, xbf, nullptr, nullptr, nullptr, N);

    // ---- conv2 GEMM ----
    gemm_qkvs2<<<gb, 256, 0, stream>>>(xbf, wt2, ba2, qb, kvb, skip, N);

    // ---- conv2 attention + fused final LN/Linear -> d_out ----
    fused_attn<0, 0, 1><<<attn_blocks, 256, 0, stream>>>(
        qb, kvb, skip, off, csr, lng, lnb, nullptr, Wf, bf, (float*)d_out, N);
}